// Round 1
// baseline (378.703 us; speedup 1.0000x reference)
//
#include <hip/hip_runtime.h>
#include <stdint.h>

#define NB 2
#define NL 2048
#define NDIM 2048
#define NH 16
#define NKV 8
#define HD 128

typedef unsigned short u16;
typedef unsigned int u32;
using f32x4 = __attribute__((ext_vector_type(4))) float;
using bf16x8 = __attribute__((ext_vector_type(8))) short;

__device__ __forceinline__ u16 f2bf(float f){
  union { float f; u32 u; } v; v.f = f;
  u32 r = v.u + 0x7fffu + ((v.u >> 16) & 1u);
  return (u16)(r >> 16);
}
__device__ __forceinline__ float bf2f(u16 u){
  union { u32 u; float f; } v; v.u = ((u32)u) << 16;
  return v.f;
}

__device__ __forceinline__ void gld_lds16(const void* g, void* l){
  __builtin_amdgcn_global_load_lds(
      (const __attribute__((address_space(1))) u32*)g,
      (__attribute__((address_space(3))) u32*)l, 16, 0, 0);
}

// ---------------- cast f32 -> bf16, vectorized ----------------
__global__ __launch_bounds__(256) void cast_f32_bf16(const float* __restrict__ in,
                                                     u16* __restrict__ out, int n4){
  int i = blockIdx.x * blockDim.x + threadIdx.x;
  int stride = gridDim.x * blockDim.x;
  for (; i < n4; i += stride){
    float4 f = ((const float4*)in)[i];
    ushort4 o;
    o.x = f2bf(f.x); o.y = f2bf(f.y); o.z = f2bf(f.z); o.w = f2bf(f.w);
    ((ushort4*)out)[i] = o;
  }
}

// ---------------- GEMM: C(M,N) = A(M,K) @ Bw(N,K)^T  (m97 structure) ----------------
// 128x128 tile, BK=32, 4 waves (each 64x64), global_load_lds w=16,
// LDS chunk XOR-swizzle s(row)=(row>>1)&3 -> 2-way (free) bank access on ds_read_b128.
template<int STORE_BF16>
__global__ __launch_bounds__(256) void gemm_bt(const u16* __restrict__ A,
    const u16* __restrict__ Bw, void* __restrict__ Cp, int M, int N, int K)
{
  __shared__ u16 As[128*32];
  __shared__ u16 Bs[128*32];
  const int tid = threadIdx.x;
  const int l = tid & 63, w = tid >> 6;
  const int wr = w >> 1, wc = w & 1;
  const int lr = l & 15, lc = l >> 4;
  const int m0 = blockIdx.y << 7, n0 = blockIdx.x << 7;

  const int srow = tid >> 2;
  const int sch = ((tid & 3) ^ ((srow >> 1) & 3)) << 3;   // swizzled k-chunk (elements)
  const u16* aG0 = A + (m0 + srow) * K + sch;
  const u16* aG1 = A + (m0 + srow + 64) * K + sch;
  const u16* bG0 = Bw + (n0 + srow) * K + sch;
  const u16* bG1 = Bw + (n0 + srow + 64) * K + sch;
  u16* aL0 = As + tid * 8;  u16* aL1 = As + 2048 + tid * 8;
  u16* bL0 = Bs + tid * 8;  u16* bL1 = Bs + 2048 + tid * 8;

  int aoff[4], boff[4];
#pragma unroll
  for (int i = 0; i < 4; ++i){
    int ra = wr*64 + i*16 + lr;
    aoff[i] = ra*32 + ((lc ^ ((ra >> 1) & 3)) << 3);
    int rb = wc*64 + i*16 + lr;
    boff[i] = rb*32 + ((lc ^ ((rb >> 1) & 3)) << 3);
  }

  f32x4 acc[4][4] = {};

  for (int kt = 0; kt < K; kt += 32){
    gld_lds16(aG0 + kt, aL0);
    gld_lds16(aG1 + kt, aL1);
    gld_lds16(bG0 + kt, bL0);
    gld_lds16(bG1 + kt, bL1);
    __syncthreads();
    bf16x8 af[4], bfr[4];
#pragma unroll
    for (int i = 0; i < 4; ++i) af[i]  = *(const bf16x8*)(As + aoff[i]);
#pragma unroll
    for (int i = 0; i < 4; ++i) bfr[i] = *(const bf16x8*)(Bs + boff[i]);
#pragma unroll
    for (int mi = 0; mi < 4; ++mi)
#pragma unroll
      for (int ni = 0; ni < 4; ++ni)
        acc[mi][ni] = __builtin_amdgcn_mfma_f32_16x16x32_bf16(af[mi], bfr[ni], acc[mi][ni], 0, 0, 0);
    __syncthreads();
  }

  // C/D layout (m89-verified): col = lane&15, row = (lane>>4)*4 + reg
#pragma unroll
  for (int mi = 0; mi < 4; ++mi)
#pragma unroll
    for (int ni = 0; ni < 4; ++ni)
#pragma unroll
      for (int r = 0; r < 4; ++r){
        int row = m0 + wr*64 + mi*16 + lc*4 + r;
        int col = n0 + wc*64 + ni*16 + lr;
        if (STORE_BF16) ((u16*)Cp)[row * N + col] = f2bf(acc[mi][ni][r]);
        else            ((float*)Cp)[row * N + col] = acc[mi][ni][r];
      }
}

// ---------------- RoPE (in-place, HF rotate_half) ----------------
__global__ __launch_bounds__(256) void rope_kernel(u16* __restrict__ q, u16* __restrict__ k,
    const float* __restrict__ cosb, const float* __restrict__ sinb)
{
  const int row = blockIdx.x;           // b*NL + l
  const int pos = row & (NL - 1);
  const float* cr = cosb + pos * HD;
  const float* sr = sinb + pos * HD;
  const int t = threadIdx.x;
  // Q: 16 heads x 64 pairs = 1024 pairs; 4 pairs/thread
  {
    const int head = t >> 4;
    const int d0 = (t & 15) << 2;
    u16* base = q + row * (NH * HD) + head * HD + d0;
    ushort4 a = *(const ushort4*)base;
    ushort4 b = *(const ushort4*)(base + 64);
    float4 c1 = *(const float4*)(cr + d0);
    float4 s1 = *(const float4*)(sr + d0);
    float4 c2 = *(const float4*)(cr + 64 + d0);
    float4 s2 = *(const float4*)(sr + 64 + d0);
    ushort4 o1, o2;
    o1.x = f2bf(bf2f(a.x)*c1.x - bf2f(b.x)*s1.x);
    o1.y = f2bf(bf2f(a.y)*c1.y - bf2f(b.y)*s1.y);
    o1.z = f2bf(bf2f(a.z)*c1.z - bf2f(b.z)*s1.z);
    o1.w = f2bf(bf2f(a.w)*c1.w - bf2f(b.w)*s1.w);
    o2.x = f2bf(bf2f(b.x)*c2.x + bf2f(a.x)*s2.x);
    o2.y = f2bf(bf2f(b.y)*c2.y + bf2f(a.y)*s2.y);
    o2.z = f2bf(bf2f(b.z)*c2.z + bf2f(a.z)*s2.z);
    o2.w = f2bf(bf2f(b.w)*c2.w + bf2f(a.w)*s2.w);
    *(ushort4*)base = o1;
    *(ushort4*)(base + 64) = o2;
  }
  // K: 8 heads x 64 pairs = 512 pairs; 2 pairs/thread
  {
    const int head = t >> 5;
    const int d0 = (t & 31) << 1;
    u16* base = k + row * (NKV * HD) + head * HD + d0;
    ushort2 a = *(const ushort2*)base;
    ushort2 b = *(const ushort2*)(base + 64);
    float2 c1 = *(const float2*)(cr + d0);
    float2 s1 = *(const float2*)(sr + d0);
    float2 c2 = *(const float2*)(cr + 64 + d0);
    float2 s2 = *(const float2*)(sr + 64 + d0);
    ushort2 o1, o2;
    o1.x = f2bf(bf2f(a.x)*c1.x - bf2f(b.x)*s1.x);
    o1.y = f2bf(bf2f(a.y)*c1.y - bf2f(b.y)*s1.y);
    o2.x = f2bf(bf2f(b.x)*c2.x + bf2f(a.x)*s2.x);
    o2.y = f2bf(bf2f(b.y)*c2.y + bf2f(a.y)*s2.y);
    *(ushort2*)base = o1;
    *(ushort2*)(base + 64) = o2;
  }
}

// ---------------- sliding-window attention ----------------
// Block = (qb, h, b). 512 thr = 8 waves x 16 q-rows. Exactly 2 KV tiles per Q block:
// tile0 = block qb-1 (keep c>=r), tile1 = block qb (keep c<=r). qb==0 -> tile1 only.
// LDS: kv[2][128][128] (K, then reused as V^T), pbuf[8][16][256]. All XOR-swizzled.
__global__ __launch_bounds__(512) void attn_sw(const u16* __restrict__ q,
    const u16* __restrict__ k, const u16* __restrict__ v, u16* __restrict__ o)
{
  extern __shared__ u16 smem[];
  u16* kv0  = smem;               // 2 * 16384 u16 = 64KB
  u16* pbuf = smem + 2 * 16384;   // 8 * 4096 u16 = 64KB

  const int qb = blockIdx.x, h = blockIdx.y, b = blockIdx.z;
  const int kvh = h >> 1;
  const int tid = threadIdx.x, l = tid & 63, w = tid >> 6;
  const int lr = l & 15, lc = l >> 4;
  const int t0 = (qb == 0) ? 1 : 0;
  const int q0 = qb * 128;
  const int kst = NKV * HD;       // 1024

  // ---- stage K tiles (swizzled global source, linear LDS dest) ----
#pragma unroll
  for (int t = 0; t < 2; ++t){
    if (t >= t0){
      const int kb = qb - 1 + t;
      const u16* kbase = k + (b * NL + kb * 128) * kst + kvh * HD;
#pragma unroll
      for (int c = 0; c < 4; ++c){
        int off = c * 8192 + tid * 16;       // byte offset in 32KB tile
        int row = off >> 8;
        int ch  = (off >> 4) & 15;
        int gch = ch ^ (row & 7);
        gld_lds16(kbase + row * kst + gch * 8, kv0 + t * 16384 + (off >> 1));
      }
    }
  }

  // ---- Q fragments from global (A-frag: row=l&15, k=(l>>4)*8+e, consistent mapping) ----
  bf16x8 aq[4];
  {
    const int qrow = b * NL + q0 + w * 16 + lr;
#pragma unroll
    for (int kc = 0; kc < 4; ++kc)
      aq[kc] = *(const bf16x8*)(q + qrow * (NH * HD) + h * HD + kc * 32 + lc * 8);
  }
  __syncthreads();

  // ---- S = Q K^T ----
  f32x4 sc[2][8] = {};
#pragma unroll
  for (int t = 0; t < 2; ++t){
    if (t >= t0){
#pragma unroll
      for (int cb = 0; cb < 8; ++cb){
        f32x4 a = {};
#pragma unroll
        for (int kc = 0; kc < 4; ++kc){
          int row = cb * 16 + lr;
          bf16x8 bk = *(const bf16x8*)(kv0 + t * 16384 +
              ((row * 256 + ((kc * 64 + lc * 16) ^ ((row & 7) << 4))) >> 1));
          a = __builtin_amdgcn_mfma_f32_16x16x32_bf16(aq[kc], bk, a, 0, 0, 0);
        }
        sc[t][cb] = a;
      }
    }
  }

  // ---- mask + scale + row max ----
  const float scale = 0.08838834764831845f;  // 128^-0.5
  float mx[4] = {-3e38f, -3e38f, -3e38f, -3e38f};
#pragma unroll
  for (int t = 0; t < 2; ++t)
#pragma unroll
    for (int cb = 0; cb < 8; ++cb)
#pragma unroll
      for (int r = 0; r < 4; ++r){
        int rbl = w * 16 + lc * 4 + r;       // block-local q row
        int c = cb * 16 + lr;                // tile-local key col
        bool keep = (t == 0) ? (t0 == 0 && c >= rbl) : (c <= rbl);
        float val = keep ? sc[t][cb][r] * scale : -1e30f;
        sc[t][cb][r] = val;
        mx[r] = fmaxf(mx[r], val);
      }
#pragma unroll
  for (int r = 0; r < 4; ++r){
    mx[r] = fmaxf(mx[r], __shfl_xor(mx[r], 1));
    mx[r] = fmaxf(mx[r], __shfl_xor(mx[r], 2));
    mx[r] = fmaxf(mx[r], __shfl_xor(mx[r], 4));
    mx[r] = fmaxf(mx[r], __shfl_xor(mx[r], 8));
  }

  // ---- exp, sum, write P to LDS (bf16, swizzled) ----
  float sm[4] = {0.f, 0.f, 0.f, 0.f};
  u16* pw = pbuf + w * 4096;
#pragma unroll
  for (int t = 0; t < 2; ++t)
#pragma unroll
    for (int cb = 0; cb < 8; ++cb)
#pragma unroll
      for (int r = 0; r < 4; ++r){
        float p = __expf(sc[t][cb][r] - mx[r]);
        sm[r] += p;
        int rr = lc * 4 + r;
        int colb = (t * 128 + cb * 16 + lr) * 2;
        pw[((rr * 512 + colb) ^ ((rr & 7) << 4)) >> 1] = f2bf(p);
      }
#pragma unroll
  for (int r = 0; r < 4; ++r){
    sm[r] += __shfl_xor(sm[r], 1);
    sm[r] += __shfl_xor(sm[r], 2);
    sm[r] += __shfl_xor(sm[r], 4);
    sm[r] += __shfl_xor(sm[r], 8);
  }

  __syncthreads();   // S done reading K; P visible

  // ---- stage V^T into kv (register transpose; writes ~conflict-free) ----
  {
    const int key = tid & 127;
    const int h2 = tid >> 7;                 // 0..3 -> d block of 32
#pragma unroll
    for (int t = 0; t < 2; ++t){
      if (t >= t0){
        const int kb = qb - 1 + t;
        const u16* vbase = v + (b * NL + kb * 128 + key) * kst + kvh * HD + h2 * 32;
        u16* dst = kv0 + t * 16384;
#pragma unroll
        for (int c2 = 0; c2 < 4; ++c2){
          union { uint4 v4; u16 s[8]; } u;
          u.v4 = *(const uint4*)(vbase + c2 * 8);
          int d0 = h2 * 32 + c2 * 8;
#pragma unroll
          for (int e = 0; e < 8; ++e){
            int d = d0 + e;
            dst[((d * 256 + key * 2) ^ ((d & 7) << 4)) >> 1] = u.s[e];
          }
        }
      }
    }
  }
  __syncthreads();

  // ---- O = P V ----
  f32x4 od[8] = {};
#pragma unroll
  for (int kc = 0; kc < 8; ++kc){
    if (kc >= t0 * 4){
      int t = kc >> 2, kl = kc & 3;
      int abyte = ((lr * 512 + (kc * 32 + lc * 8) * 2) ^ ((lr & 7) << 4));
      bf16x8 pa = *(const bf16x8*)(pbuf + w * 4096 + (abyte >> 1));
#pragma unroll
      for (int cb = 0; cb < 8; ++cb){
        int d = cb * 16 + lr;
        bf16x8 vb = *(const bf16x8*)(kv0 + t * 16384 +
            ((d * 256 + ((kl * 64 + lc * 16) ^ ((d & 7) << 4))) >> 1));
        od[cb] = __builtin_amdgcn_mfma_f32_16x16x32_bf16(pa, vb, od[cb], 0, 0, 0);
      }
    }
  }

  // ---- normalize + store ----
  float inv[4];
#pragma unroll
  for (int r = 0; r < 4; ++r) inv[r] = 1.0f / sm[r];
#pragma unroll
  for (int cb = 0; cb < 8; ++cb)
#pragma unroll
    for (int r = 0; r < 4; ++r){
      int orow = b * NL + q0 + w * 16 + lc * 4 + r;
      int ocol = h * HD + cb * 16 + lr;
      o[orow * (NH * HD) + ocol] = f2bf(od[cb][r] * inv[r]);
    }
}

// ---------------- launcher ----------------
extern "C" void kernel_launch(void* const* d_in, const int* in_sizes, int n_in,
                              void* d_out, int out_size, void* d_ws, size_t ws_size,
                              hipStream_t stream)
{
  const float* x    = (const float*)d_in[0];
  const float* cosb = (const float*)d_in[1];
  const float* sinb = (const float*)d_in[2];
  const float* wq   = (const float*)d_in[3];
  const float* wk   = (const float*)d_in[4];
  const float* wv   = (const float*)d_in[5];
  const float* wo   = (const float*)d_in[6];

  u16* p = (u16*)d_ws;
  u16* xb  = p; p += NB * NL * NDIM;
  u16* wqb = p; p += NH * HD * NDIM;
  u16* wkb = p; p += NKV * HD * NDIM;
  u16* wvb = p; p += NKV * HD * NDIM;
  u16* wob = p; p += NDIM * NH * HD;
  u16* qb  = p; p += NB * NL * NH * HD;
  u16* kb  = p; p += NB * NL * NKV * HD;
  u16* vb  = p; p += NB * NL * NKV * HD;
  u16* ab  = p; p += NB * NL * NH * HD;

  cast_f32_bf16<<<2048, 256, 0, stream>>>(x,  xb,  NB * NL * NDIM / 4);
  cast_f32_bf16<<<1024, 256, 0, stream>>>(wq, wqb, NH * HD * NDIM / 4);
  cast_f32_bf16<<<512,  256, 0, stream>>>(wk, wkb, NKV * HD * NDIM / 4);
  cast_f32_bf16<<<512,  256, 0, stream>>>(wv, wvb, NKV * HD * NDIM / 4);
  cast_f32_bf16<<<1024, 256, 0, stream>>>(wo, wob, NDIM * NH * HD / 4);

  gemm_bt<1><<<dim3(NH * HD / 128, NB * NL / 128), 256, 0, stream>>>(xb, wqb, qb, NB * NL, NH * HD, NDIM);
  gemm_bt<1><<<dim3(NKV * HD / 128, NB * NL / 128), 256, 0, stream>>>(xb, wkb, kb, NB * NL, NKV * HD, NDIM);
  gemm_bt<1><<<dim3(NKV * HD / 128, NB * NL / 128), 256, 0, stream>>>(xb, wvb, vb, NB * NL, NKV * HD, NDIM);

  rope_kernel<<<NB * NL, 256, 0, stream>>>(qb, kb, cosb, sinb);

  hipFuncSetAttribute(reinterpret_cast<const void*>(attn_sw),
                      hipFuncAttributeMaxDynamicSharedMemorySize, 131072);
  attn_sw<<<dim3(NL / 128, NH, NB), 512, 131072, stream>>>(qb, kb, vb, ab);

  gemm_bt<0><<<dim3(NDIM / 128, NB * NL / 128), 256, 0, stream>>>(ab, wob, d_out, NB * NL, NDIM, NH * HD);
}

// Round 2
// 332.314 us; speedup vs baseline: 1.1396x; 1.1396x over previous
//
#include <hip/hip_runtime.h>
#include <stdint.h>

#define NB 2
#define NL 2048
#define NDIM 2048
#define NH 16
#define NKV 8
#define HD 128

typedef unsigned short u16;
typedef unsigned int u32;
using f32x4 = __attribute__((ext_vector_type(4))) float;
using bf16x8 = __attribute__((ext_vector_type(8))) short;

__device__ __forceinline__ u16 f2bf(float f){
  union { float f; u32 u; } v; v.f = f;
  u32 r = v.u + 0x7fffu + ((v.u >> 16) & 1u);
  return (u16)(r >> 16);
}
__device__ __forceinline__ float bf2f(u16 u){
  union { u32 u; float f; } v; v.u = ((u32)u) << 16;
  return v.f;
}

__device__ __forceinline__ void gld_lds16(const void* g, void* l){
  __builtin_amdgcn_global_load_lds(
      (const __attribute__((address_space(1))) u32*)g,
      (__attribute__((address_space(3))) u32*)l, 16, 0, 0);
}

// ---------------- fused cast f32 -> bf16 (x, wq, wk, wv, wo -> contiguous ws) ---------
#define X4   (NB*NL*NDIM/4)
#define WQ4  (NH*HD*NDIM/4)
#define WK4  (NKV*HD*NDIM/4)
#define WV4  (NKV*HD*NDIM/4)
#define WO4  (NDIM*NH*HD/4)
#define TOT4 (X4+WQ4+WK4+WV4+WO4)

__global__ __launch_bounds__(256) void cast_all(const float* __restrict__ x,
    const float* __restrict__ wq, const float* __restrict__ wk,
    const float* __restrict__ wv, const float* __restrict__ wo,
    u16* __restrict__ dst)
{
  int i = blockIdx.x * blockDim.x + threadIdx.x;
  int stride = gridDim.x * blockDim.x;
  for (; i < TOT4; i += stride){
    const float* src; int off;
    if      (i < X4)                 { src = x;  off = i; }
    else if (i < X4+WQ4)             { src = wq; off = i - X4; }
    else if (i < X4+WQ4+WK4)         { src = wk; off = i - (X4+WQ4); }
    else if (i < X4+WQ4+WK4+WV4)     { src = wv; off = i - (X4+WQ4+WK4); }
    else                             { src = wo; off = i - (X4+WQ4+WK4+WV4); }
    float4 f = ((const float4*)src)[off];
    ushort4 o;
    o.x = f2bf(f.x); o.y = f2bf(f.y); o.z = f2bf(f.z); o.w = f2bf(f.w);
    ((ushort4*)dst)[i] = o;
  }
}

// ---------------- GEMM: C(M,N) = A(M,K) @ Bw(N,K)^T  (m97 structure + T1 swizzle) ----
// MODE 0: f32 plain out. MODE 2: bf16 out routed to q/k/v buffers (col<2048 -> q,
// col<3072 -> k, else v). 128x128 tile, BK=32, 4 waves, gld_lds w=16, XOR chunk swizzle.
template<int MODE>
__global__ __launch_bounds__(256) void gemm_bt(const u16* __restrict__ A,
    const u16* __restrict__ Bw, void* __restrict__ Cp, u16* __restrict__ ko,
    u16* __restrict__ vo, int M, int N, int K)
{
  __shared__ u16 As[128*32];
  __shared__ u16 Bs[128*32];
  const int tid = threadIdx.x;
  const int l = tid & 63, w = tid >> 6;
  const int wr = w >> 1, wc = w & 1;
  const int lr = l & 15, lc = l >> 4;

  // T1: bijective XCD-chunked swizzle (nwg % 8 == 0 for all our grids)
  const int nwg = gridDim.x * gridDim.y;
  const int orig = blockIdx.y * gridDim.x + blockIdx.x;
  const int cpx = nwg >> 3;
  const int work = (orig & 7) * cpx + (orig >> 3);
  const int lgx = 31 - __clz(gridDim.x);
  const int bx = work & (gridDim.x - 1);
  const int by = work >> lgx;

  const int m0 = by << 7, n0 = bx << 7;

  const int srow = tid >> 2;
  const int sch = ((tid & 3) ^ ((srow >> 1) & 3)) << 3;   // swizzled k-chunk (elements)
  const u16* aG0 = A + (m0 + srow) * K + sch;
  const u16* aG1 = A + (m0 + srow + 64) * K + sch;
  const u16* bG0 = Bw + (n0 + srow) * K + sch;
  const u16* bG1 = Bw + (n0 + srow + 64) * K + sch;
  u16* aL0 = As + tid * 8;  u16* aL1 = As + 2048 + tid * 8;
  u16* bL0 = Bs + tid * 8;  u16* bL1 = Bs + 2048 + tid * 8;

  int aoff[4], boff[4];
#pragma unroll
  for (int i = 0; i < 4; ++i){
    int ra = wr*64 + i*16 + lr;
    aoff[i] = ra*32 + ((lc ^ ((ra >> 1) & 3)) << 3);
    int rb = wc*64 + i*16 + lr;
    boff[i] = rb*32 + ((lc ^ ((rb >> 1) & 3)) << 3);
  }

  f32x4 acc[4][4] = {};

  for (int kt = 0; kt < K; kt += 32){
    gld_lds16(aG0 + kt, aL0);
    gld_lds16(aG1 + kt, aL1);
    gld_lds16(bG0 + kt, bL0);
    gld_lds16(bG1 + kt, bL1);
    __syncthreads();
    bf16x8 af[4], bfr[4];
#pragma unroll
    for (int i = 0; i < 4; ++i) af[i]  = *(const bf16x8*)(As + aoff[i]);
#pragma unroll
    for (int i = 0; i < 4; ++i) bfr[i] = *(const bf16x8*)(Bs + boff[i]);
#pragma unroll
    for (int mi = 0; mi < 4; ++mi)
#pragma unroll
      for (int ni = 0; ni < 4; ++ni)
        acc[mi][ni] = __builtin_amdgcn_mfma_f32_16x16x32_bf16(af[mi], bfr[ni], acc[mi][ni], 0, 0, 0);
    __syncthreads();
  }

  // C/D layout (m89-verified): col = lane&15, row = (lane>>4)*4 + reg
#pragma unroll
  for (int mi = 0; mi < 4; ++mi)
#pragma unroll
    for (int ni = 0; ni < 4; ++ni){
      const int colg = n0 + wc*64 + ni*16 + lr;
#pragma unroll
      for (int r = 0; r < 4; ++r){
        const int row = m0 + wr*64 + mi*16 + lc*4 + r;
        if (MODE == 0){
          ((float*)Cp)[row * N + colg] = acc[mi][ni][r];
        } else {
          u16 val = f2bf(acc[mi][ni][r]);
          if (colg < 2048)      ((u16*)Cp)[row * 2048 + colg] = val;
          else if (colg < 3072) ko[row * 1024 + (colg - 2048)] = val;
          else                  vo[row * 1024 + (colg - 3072)] = val;
        }
      }
    }
}

// ---------------- RoPE (in-place, HF rotate_half) ----------------
__global__ __launch_bounds__(256) void rope_kernel(u16* __restrict__ q, u16* __restrict__ k,
    const float* __restrict__ cosb, const float* __restrict__ sinb)
{
  const int row = blockIdx.x;           // b*NL + l
  const int pos = row & (NL - 1);
  const float* cr = cosb + pos * HD;
  const float* sr = sinb + pos * HD;
  const int t = threadIdx.x;
  {
    const int head = t >> 4;
    const int d0 = (t & 15) << 2;
    u16* base = q + row * (NH * HD) + head * HD + d0;
    ushort4 a = *(const ushort4*)base;
    ushort4 b = *(const ushort4*)(base + 64);
    float4 c1 = *(const float4*)(cr + d0);
    float4 s1 = *(const float4*)(sr + d0);
    float4 c2 = *(const float4*)(cr + 64 + d0);
    float4 s2 = *(const float4*)(sr + 64 + d0);
    ushort4 o1, o2;
    o1.x = f2bf(bf2f(a.x)*c1.x - bf2f(b.x)*s1.x);
    o1.y = f2bf(bf2f(a.y)*c1.y - bf2f(b.y)*s1.y);
    o1.z = f2bf(bf2f(a.z)*c1.z - bf2f(b.z)*s1.z);
    o1.w = f2bf(bf2f(a.w)*c1.w - bf2f(b.w)*s1.w);
    o2.x = f2bf(bf2f(b.x)*c2.x + bf2f(a.x)*s2.x);
    o2.y = f2bf(bf2f(b.y)*c2.y + bf2f(a.y)*s2.y);
    o2.z = f2bf(bf2f(b.z)*c2.z + bf2f(a.z)*s2.z);
    o2.w = f2bf(bf2f(b.w)*c2.w + bf2f(a.w)*s2.w);
    *(ushort4*)base = o1;
    *(ushort4*)(base + 64) = o2;
  }
  {
    const int head = t >> 5;
    const int d0 = (t & 31) << 1;
    u16* base = k + row * (NKV * HD) + head * HD + d0;
    ushort2 a = *(const ushort2*)base;
    ushort2 b = *(const ushort2*)(base + 64);
    float2 c1 = *(const float2*)(cr + d0);
    float2 s1 = *(const float2*)(sr + d0);
    float2 c2 = *(const float2*)(cr + 64 + d0);
    float2 s2 = *(const float2*)(sr + 64 + d0);
    ushort2 o1, o2;
    o1.x = f2bf(bf2f(a.x)*c1.x - bf2f(b.x)*s1.x);
    o1.y = f2bf(bf2f(a.y)*c1.y - bf2f(b.y)*s1.y);
    o2.x = f2bf(bf2f(b.x)*c2.x + bf2f(a.x)*s2.x);
    o2.y = f2bf(bf2f(b.y)*c2.y + bf2f(a.y)*s2.y);
    *(ushort2*)base = o1;
    *(ushort2*)(base + 64) = o2;
  }
}

// ---------------- sliding-window attention (masked-fragment skip + setprio) ----------
// Block = (qb, h, b). 512 thr = 8 waves x 16 q-rows. 2 KV tiles per Q block:
// tile0 = block qb-1 (keep c>=r -> only cb>=w live), tile1 = qb (keep c<=r -> cb<=w).
// PV reads kc=(t,kl) iff its cb-pair has a live member; exactly 5 of 8 kc per wave.
__global__ __launch_bounds__(512) void attn_sw(const u16* __restrict__ q,
    const u16* __restrict__ k, const u16* __restrict__ v, u16* __restrict__ o)
{
  extern __shared__ u16 smem[];
  u16* kv0  = smem;               // 2 * 16384 u16 = 64KB
  u16* pbuf = smem + 2 * 16384;   // 8 * 4096 u16 = 64KB

  const int qb = blockIdx.x, h = blockIdx.y, b = blockIdx.z;
  const int kvh = h >> 1;
  const int tid = threadIdx.x, l = tid & 63, w = tid >> 6;
  const int lr = l & 15, lc = l >> 4;
  const int t0 = (qb == 0) ? 1 : 0;
  const int q0 = qb * 128;
  const int kst = NKV * HD;       // 1024

  // ---- stage K tiles (swizzled global source, linear LDS dest) ----
#pragma unroll
  for (int t = 0; t < 2; ++t){
    if (t >= t0){
      const int kb = qb - 1 + t;
      const u16* kbase = k + (b * NL + kb * 128) * kst + kvh * HD;
#pragma unroll
      for (int c = 0; c < 4; ++c){
        int off = c * 8192 + tid * 16;       // byte offset in 32KB tile
        int row = off >> 8;
        int ch  = (off >> 4) & 15;
        int gch = ch ^ (row & 7);
        gld_lds16(kbase + row * kst + gch * 8, kv0 + t * 16384 + (off >> 1));
      }
    }
  }

  // ---- Q fragments from global (A-frag: row=l&15, k=(l>>4)*8+e, consistent mapping) --
  bf16x8 aq[4];
  {
    const int qrow = b * NL + q0 + w * 16 + lr;
#pragma unroll
    for (int kc = 0; kc < 4; ++kc)
      aq[kc] = *(const bf16x8*)(q + qrow * (NH * HD) + h * HD + kc * 32 + lc * 8);
  }
  __syncthreads();

  // ---- S = Q K^T (skip fully-masked fragments) ----
  f32x4 sc[2][8] = {};
  __builtin_amdgcn_s_setprio(1);
#pragma unroll
  for (int t = 0; t < 2; ++t){
#pragma unroll
    for (int cb = 0; cb < 8; ++cb){
      const bool live = (t == 0) ? (t0 == 0 && cb >= w) : (cb <= w);
      if (live){
        f32x4 a = {};
#pragma unroll
        for (int kc = 0; kc < 4; ++kc){
          int row = cb * 16 + lr;
          bf16x8 bk = *(const bf16x8*)(kv0 + t * 16384 +
              ((row * 256 + ((kc * 64 + lc * 16) ^ ((row & 7) << 4))) >> 1));
          a = __builtin_amdgcn_mfma_f32_16x16x32_bf16(aq[kc], bk, a, 0, 0, 0);
        }
        sc[t][cb] = a;
      }
    }
  }
  __builtin_amdgcn_s_setprio(0);

  // ---- mask + scale + row max (live fragments only) ----
  const float scale = 0.08838834764831845f;  // 128^-0.5
  float mx[4] = {-3e38f, -3e38f, -3e38f, -3e38f};
#pragma unroll
  for (int t = 0; t < 2; ++t)
#pragma unroll
    for (int cb = 0; cb < 8; ++cb){
      const bool liveF = (t == 0) ? (t0 == 0 && cb >= w) : (cb <= w);
      if (liveF){
#pragma unroll
        for (int r = 0; r < 4; ++r){
          int rbl = w * 16 + lc * 4 + r;       // block-local q row
          int c = cb * 16 + lr;                // tile-local key col
          bool keep = (t == 0) ? (c >= rbl) : (c <= rbl);
          float val = keep ? sc[t][cb][r] * scale : -1e30f;
          sc[t][cb][r] = val;
          mx[r] = fmaxf(mx[r], val);
        }
      }
    }
#pragma unroll
  for (int r = 0; r < 4; ++r){
    mx[r] = fmaxf(mx[r], __shfl_xor(mx[r], 1));
    mx[r] = fmaxf(mx[r], __shfl_xor(mx[r], 2));
    mx[r] = fmaxf(mx[r], __shfl_xor(mx[r], 4));
    mx[r] = fmaxf(mx[r], __shfl_xor(mx[r], 8));
  }

  // ---- exp, sum, write P to LDS (bf16, swizzled); zero-fill dead-but-read frags ----
  float sm[4] = {0.f, 0.f, 0.f, 0.f};
  u16* pw = pbuf + w * 4096;
#pragma unroll
  for (int t = 0; t < 2; ++t)
#pragma unroll
    for (int cb = 0; cb < 8; ++cb){
      const bool liveC = (t == 0) ? (t0 == 0 && cb >= w) : (cb <= w);
      const bool readN = (t == 0) ? (t0 == 0 && (cb | 1) >= w) : ((cb & ~1) <= w);
      if (liveC){
#pragma unroll
        for (int r = 0; r < 4; ++r){
          float p = __expf(sc[t][cb][r] - mx[r]);
          sm[r] += p;
          int rr = lc * 4 + r;
          int colb = (t * 128 + cb * 16 + lr) * 2;
          pw[((rr * 512 + colb) ^ ((rr & 7) << 4)) >> 1] = f2bf(p);
        }
      } else if (readN){
#pragma unroll
        for (int r = 0; r < 4; ++r){
          int rr = lc * 4 + r;
          int colb = (t * 128 + cb * 16 + lr) * 2;
          pw[((rr * 512 + colb) ^ ((rr & 7) << 4)) >> 1] = 0;   // bf16 +0.0
        }
      }
    }
#pragma unroll
  for (int r = 0; r < 4; ++r){
    sm[r] += __shfl_xor(sm[r], 1);
    sm[r] += __shfl_xor(sm[r], 2);
    sm[r] += __shfl_xor(sm[r], 4);
    sm[r] += __shfl_xor(sm[r], 8);
  }

  __syncthreads();   // S done reading K; P visible

  // ---- stage V^T into kv (register transpose; writes ~conflict-free) ----
  {
    const int key = tid & 127;
    const int h2 = tid >> 7;                 // 0..3 -> d block of 32
#pragma unroll
    for (int t = 0; t < 2; ++t){
      if (t >= t0){
        const int kb = qb - 1 + t;
        const u16* vbase = v + (b * NL + kb * 128 + key) * kst + kvh * HD + h2 * 32;
        u16* dst = kv0 + t * 16384;
#pragma unroll
        for (int c2 = 0; c2 < 4; ++c2){
          union { uint4 v4; u16 s[8]; } u;
          u.v4 = *(const uint4*)(vbase + c2 * 8);
          int d0 = h2 * 32 + c2 * 8;
#pragma unroll
          for (int e = 0; e < 8; ++e){
            int d = d0 + e;
            dst[((d * 256 + key * 2) ^ ((d & 7) << 4)) >> 1] = u.s[e];
          }
        }
      }
    }
  }
  __syncthreads();

  // ---- O = P V (skip kc whose cb-pair is fully dead: 5 of 8 live) ----
  f32x4 od[8] = {};
  __builtin_amdgcn_s_setprio(1);
#pragma unroll
  for (int kc = 0; kc < 8; ++kc){
    const int t = kc >> 2, kl = kc & 3;
    const bool live = (t == 0) ? (t0 == 0 && (kl * 2 + 1) >= w) : (kl * 2 <= w);
    if (live){
      int abyte = ((lr * 512 + (kc * 32 + lc * 8) * 2) ^ ((lr & 7) << 4));
      bf16x8 pa = *(const bf16x8*)(pbuf + w * 4096 + (abyte >> 1));
#pragma unroll
      for (int cb = 0; cb < 8; ++cb){
        int d = cb * 16 + lr;
        bf16x8 vb = *(const bf16x8*)(kv0 + t * 16384 +
            ((d * 256 + ((kl * 64 + lc * 16) ^ ((d & 7) << 4))) >> 1));
        od[cb] = __builtin_amdgcn_mfma_f32_16x16x32_bf16(pa, vb, od[cb], 0, 0, 0);
      }
    }
  }
  __builtin_amdgcn_s_setprio(0);

  // ---- normalize + store ----
  float inv[4];
#pragma unroll
  for (int r = 0; r < 4; ++r) inv[r] = 1.0f / sm[r];
#pragma unroll
  for (int cb = 0; cb < 8; ++cb)
#pragma unroll
    for (int r = 0; r < 4; ++r){
      int orow = b * NL + q0 + w * 16 + lc * 4 + r;
      int ocol = h * HD + cb * 16 + lr;
      o[orow * (NH * HD) + ocol] = f2bf(od[cb][r] * inv[r]);
    }
}

// ---------------- launcher ----------------
extern "C" void kernel_launch(void* const* d_in, const int* in_sizes, int n_in,
                              void* d_out, int out_size, void* d_ws, size_t ws_size,
                              hipStream_t stream)
{
  const float* x    = (const float*)d_in[0];
  const float* cosb = (const float*)d_in[1];
  const float* sinb = (const float*)d_in[2];
  const float* wq   = (const float*)d_in[3];
  const float* wk   = (const float*)d_in[4];
  const float* wv   = (const float*)d_in[5];
  const float* wo   = (const float*)d_in[6];

  u16* p = (u16*)d_ws;
  u16* xb   = p; p += NB * NL * NDIM;
  u16* wqkv = p; p += (NH + 2 * NKV) * HD * NDIM;   // wq|wk|wv contiguous
  u16* wob  = p; p += NDIM * NH * HD;
  u16* qb   = p; p += NB * NL * NH * HD;
  u16* kb   = p; p += NB * NL * NKV * HD;
  u16* vb   = p; p += NB * NL * NKV * HD;
  u16* ab   = p; p += NB * NL * NH * HD;

  cast_all<<<2048, 256, 0, stream>>>(x, wq, wk, wv, wo, xb);

  // fused QKV projection: M=4096, N=4096, K=2048; epilogue routes cols to q/k/v
  gemm_bt<2><<<dim3(32, 32), 256, 0, stream>>>(xb, wqkv, qb, kb, vb,
                                               NB * NL, (NH + 2 * NKV) * HD, NDIM);

  rope_kernel<<<NB * NL, 256, 0, stream>>>(qb, kb, cosb, sinb);

  hipFuncSetAttribute(reinterpret_cast<const void*>(attn_sw),
                      hipFuncAttributeMaxDynamicSharedMemorySize, 131072);
  attn_sw<<<dim3(NL / 128, NH, NB), 512, 131072, stream>>>(qb, kb, vb, ab);

  gemm_bt<0><<<dim3(NDIM / 128, NB * NL / 128), 256, 0, stream>>>(
      ab, wob, d_out, nullptr, nullptr, NB * NL, NDIM, NH * HD);
}

// Round 3
// 291.967 us; speedup vs baseline: 1.2971x; 1.1382x over previous
//
#include <hip/hip_runtime.h>
#include <stdint.h>

#define NB 2
#define NL 2048
#define NDIM 2048
#define NH 16
#define NKV 8
#define HD 128

typedef unsigned short u16;
typedef unsigned int u32;
using f32x4 = __attribute__((ext_vector_type(4))) float;
using bf16x8 = __attribute__((ext_vector_type(8))) short;

__device__ __forceinline__ u16 f2bf(float f){
  union { float f; u32 u; } v; v.f = f;
  u32 r = v.u + 0x7fffu + ((v.u >> 16) & 1u);
  return (u16)(r >> 16);
}
__device__ __forceinline__ float bf2f(u16 u){
  union { u32 u; float f; } v; v.u = ((u32)u) << 16;
  return v.f;
}

__device__ __forceinline__ void gld_lds16(const void* g, void* l){
  __builtin_amdgcn_global_load_lds(
      (const __attribute__((address_space(1))) u32*)g,
      (__attribute__((address_space(3))) u32*)l, 16, 0, 0);
}

// ---------------- fused cast f32 -> bf16 (x, wq, wk, wv, wo -> contiguous ws) ---------
#define X4   (NB*NL*NDIM/4)
#define WQ4  (NH*HD*NDIM/4)
#define WK4  (NKV*HD*NDIM/4)
#define WV4  (NKV*HD*NDIM/4)
#define WO4  (NDIM*NH*HD/4)
#define TOT4 (X4+WQ4+WK4+WV4+WO4)

__global__ __launch_bounds__(256) void cast_all(const float* __restrict__ x,
    const float* __restrict__ wq, const float* __restrict__ wk,
    const float* __restrict__ wv, const float* __restrict__ wo,
    u16* __restrict__ dst)
{
  int i = blockIdx.x * blockDim.x + threadIdx.x;
  int stride = gridDim.x * blockDim.x;
  for (; i < TOT4; i += stride){
    const float* src; int off;
    if      (i < X4)                 { src = x;  off = i; }
    else if (i < X4+WQ4)             { src = wq; off = i - X4; }
    else if (i < X4+WQ4+WK4)         { src = wk; off = i - (X4+WQ4); }
    else if (i < X4+WQ4+WK4+WV4)     { src = wv; off = i - (X4+WQ4+WK4); }
    else                             { src = wo; off = i - (X4+WQ4+WK4+WV4); }
    float4 f = ((const float4*)src)[off];
    ushort4 o;
    o.x = f2bf(f.x); o.y = f2bf(f.y); o.z = f2bf(f.z); o.w = f2bf(f.w);
    ((ushort4*)dst)[i] = o;
  }
}

// ================= 256x256 8-phase GEMM (m201 template, plain HIP) =================
// C(M,N) = A(M,K) @ Bw(N,K)^T. BM=BN=256, BK=64, 512 thr = 8 waves (2M x 4N).
// LDS 128KB: dbuf x {A 32KB, B 32KB}. Tile layout: [rowBlk16][colBlk32][16][32] bf16
// subtiles (1024B), st_16x32 swizzle: byte ^= ((r&8)<<2) within subtile.
// global_load_lds writes LINEAR LDS; the global SOURCE address is inverse-swizzled.
// Phases per K-tile: P0{12 ds_read: A[0-3],B[0-1]; issue A-h0(u+1)} -> Q0(mi0-3,ni0-1)
//                    P1{4: B[2-3];  issue A-h1(u+1)} -> Q1(mi0-3,ni2-3)
//                    P2{8: A[4-7];  issue B-h0(u+2)} -> Q2(mi4-7,ni0-1)
//                    P3{0;          issue B-h1(u+2)} -> Q3(mi4-7,ni2-3); vmcnt(4)
// Safety: every prefetch-issue targets a region whose last ds_read finished >=1
// barrier earlier; counted vmcnt(4) + barrier at each tile boundary guarantees
// landing of tile u+? data (last 4 outstanding loads are always the 2 newest halves).
// MODE 0: f32 out. MODE 2: bf16 out routed to q/k/v (col<2048 / <3072 / else).
template<int MODE>
__global__ __launch_bounds__(512, 2) void gemm8p(const u16* __restrict__ A,
    const u16* __restrict__ Bw, void* __restrict__ Cp, u16* __restrict__ ko,
    u16* __restrict__ vo, int M, int N, int K)
{
  extern __shared__ char lds[];
  const int tid = threadIdx.x;
  const int l = tid & 63, w = tid >> 6;
  const int wm = w >> 2, wn = w & 3;        // wave grid 2 x 4
  const int r = l & 15, cq = l >> 4;
  const int m0 = blockIdx.y << 8, n0 = blockIdx.x << 8;
  const int T = K >> 6;

  // per-lane ds_read offset within a 1024B subtile (b128 of row r, k-quad cq)
  const int laneOff = (r * 64 + cq * 16) ^ ((r & 8) << 2);

  // staging decode: linear LDS byte L -> (row,col) of the swizzled subtiled layout
  int stL[4];                 // idx = h*2+g
  const u16* gA[4]; const u16* gB[4];
#pragma unroll
  for (int h = 0; h < 2; ++h)
#pragma unroll
    for (int g = 0; g < 2; ++g){
      int idx = h * 2 + g;
      int L = h * 16384 + (g * 512 + tid) * 16;
      int s  = L >> 10;
      int rr = (L >> 6) & 15;
      int c2 = (L & 63) ^ ((rr & 8) << 2);
      int row = ((s >> 1) << 4) | rr;
      int col = ((s & 1) << 5) | (c2 >> 1);
      stL[idx] = L;
      gA[idx] = A  + (size_t)(m0 + row) * K + col;
      gB[idx] = Bw + (size_t)(n0 + row) * K + col;
    }

#define ISSUE_A(h, v) do { if ((v) < T){ int _b = ((v) & 1) << 16;            \
    gld_lds16(gA[(h)*2+0] + (v)*64, lds + _b + stL[(h)*2+0]);                 \
    gld_lds16(gA[(h)*2+1] + (v)*64, lds + _b + stL[(h)*2+1]); } } while(0)
#define ISSUE_B(h, v) do { if ((v) < T){ int _b = (((v) & 1) << 16) + 32768;  \
    gld_lds16(gB[(h)*2+0] + (v)*64, lds + _b + stL[(h)*2+0]);                 \
    gld_lds16(gB[(h)*2+1] + (v)*64, lds + _b + stL[(h)*2+1]); } } while(0)

#define LDA(mi, kk) (*(const bf16x8*)(lds + bb + ((((wm*8+(mi))*2+(kk))) << 10) + laneOff))
#define LDB(ni, kk) (*(const bf16x8*)(lds + bb + 32768 + ((((wn*4+(ni))*2+(kk))) << 10) + laneOff))

#define BAR()    __builtin_amdgcn_s_barrier()
#define LGKM0()  do { asm volatile("s_waitcnt lgkmcnt(0)" ::: "memory"); \
                      __builtin_amdgcn_sched_barrier(0); } while(0)

  // ---- prologue: A(0), B(0) -> buf0; B(1) -> buf1 ----
  ISSUE_A(0, 0); ISSUE_A(1, 0);
  ISSUE_B(0, 0); ISSUE_B(1, 0);
  ISSUE_B(0, 1); ISSUE_B(1, 1);
  asm volatile("s_waitcnt vmcnt(4)" ::: "memory");   // A(0),B(0) landed
  BAR();

  f32x4 acc[8][4] = {};
  bf16x8 av[4][2], bv[4][2];

  for (int u = 0; u < T; ++u){
    const int bb = (u & 1) << 16;
    // ---------- P0 ----------
#pragma unroll
    for (int mi = 0; mi < 4; ++mi){ av[mi][0] = LDA(mi, 0); av[mi][1] = LDA(mi, 1); }
#pragma unroll
    for (int ni = 0; ni < 2; ++ni){ bv[ni][0] = LDB(ni, 0); bv[ni][1] = LDB(ni, 1); }
    ISSUE_A(0, u + 1);
    BAR(); LGKM0();
    __builtin_amdgcn_s_setprio(1);
#pragma unroll
    for (int kk = 0; kk < 2; ++kk)
#pragma unroll
      for (int mi = 0; mi < 4; ++mi)
#pragma unroll
        for (int ni = 0; ni < 2; ++ni)
          acc[mi][ni] = __builtin_amdgcn_mfma_f32_16x16x32_bf16(av[mi][kk], bv[ni][kk], acc[mi][ni], 0, 0, 0);
    __builtin_amdgcn_s_setprio(0);
    BAR();
    // ---------- P1 ----------
#pragma unroll
    for (int ni = 2; ni < 4; ++ni){ bv[ni][0] = LDB(ni, 0); bv[ni][1] = LDB(ni, 1); }
    ISSUE_A(1, u + 1);
    BAR(); LGKM0();
    __builtin_amdgcn_s_setprio(1);
#pragma unroll
    for (int kk = 0; kk < 2; ++kk)
#pragma unroll
      for (int mi = 0; mi < 4; ++mi)
#pragma unroll
        for (int ni = 2; ni < 4; ++ni)
          acc[mi][ni] = __builtin_amdgcn_mfma_f32_16x16x32_bf16(av[mi][kk], bv[ni][kk], acc[mi][ni], 0, 0, 0);
    __builtin_amdgcn_s_setprio(0);
    BAR();
    // ---------- P2 ----------
#pragma unroll
    for (int mi = 0; mi < 4; ++mi){ av[mi][0] = LDA(mi + 4, 0); av[mi][1] = LDA(mi + 4, 1); }
    ISSUE_B(0, u + 2);
    BAR(); LGKM0();
    __builtin_amdgcn_s_setprio(1);
#pragma unroll
    for (int kk = 0; kk < 2; ++kk)
#pragma unroll
      for (int mi = 0; mi < 4; ++mi)
#pragma unroll
        for (int ni = 0; ni < 2; ++ni)
          acc[mi + 4][ni] = __builtin_amdgcn_mfma_f32_16x16x32_bf16(av[mi][kk], bv[ni][kk], acc[mi + 4][ni], 0, 0, 0);
    __builtin_amdgcn_s_setprio(0);
    BAR();
    // ---------- P3 ----------
    ISSUE_B(1, u + 2);
    BAR(); LGKM0();
    __builtin_amdgcn_s_setprio(1);
#pragma unroll
    for (int kk = 0; kk < 2; ++kk)
#pragma unroll
      for (int mi = 0; mi < 4; ++mi)
#pragma unroll
        for (int ni = 2; ni < 4; ++ni)
          acc[mi + 4][ni] = __builtin_amdgcn_mfma_f32_16x16x32_bf16(av[mi][kk], bv[ni][kk], acc[mi + 4][ni], 0, 0, 0);
    __builtin_amdgcn_s_setprio(0);
    asm volatile("s_waitcnt vmcnt(4)" ::: "memory");   // next tile's A,B landed
    BAR();
  }

  // ---- epilogue: C/D layout col=lane&15, row=(lane>>4)*4+reg (m89-verified) ----
#pragma unroll
  for (int mi = 0; mi < 8; ++mi)
#pragma unroll
    for (int ni = 0; ni < 4; ++ni){
      const int colg = n0 + wn * 64 + ni * 16 + r;
#pragma unroll
      for (int rg = 0; rg < 4; ++rg){
        const int row = m0 + wm * 128 + mi * 16 + cq * 4 + rg;
        if (MODE == 0){
          ((float*)Cp)[(size_t)row * N + colg] = acc[mi][ni][rg];
        } else {
          u16 val = f2bf(acc[mi][ni][rg]);
          if (colg < 2048)      ((u16*)Cp)[row * 2048 + colg] = val;
          else if (colg < 3072) ko[row * 1024 + (colg - 2048)] = val;
          else                  vo[row * 1024 + (colg - 3072)] = val;
        }
      }
    }
#undef ISSUE_A
#undef ISSUE_B
#undef LDA
#undef LDB
#undef BAR
#undef LGKM0
}

// ---------------- RoPE (in-place, HF rotate_half) ----------------
__global__ __launch_bounds__(256) void rope_kernel(u16* __restrict__ q, u16* __restrict__ k,
    const float* __restrict__ cosb, const float* __restrict__ sinb)
{
  const int row = blockIdx.x;           // b*NL + l
  const int pos = row & (NL - 1);
  const float* cr = cosb + pos * HD;
  const float* sr = sinb + pos * HD;
  const int t = threadIdx.x;
  {
    const int head = t >> 4;
    const int d0 = (t & 15) << 2;
    u16* base = q + row * (NH * HD) + head * HD + d0;
    ushort4 a = *(const ushort4*)base;
    ushort4 b = *(const ushort4*)(base + 64);
    float4 c1 = *(const float4*)(cr + d0);
    float4 s1 = *(const float4*)(sr + d0);
    float4 c2 = *(const float4*)(cr + 64 + d0);
    float4 s2 = *(const float4*)(sr + 64 + d0);
    ushort4 o1, o2;
    o1.x = f2bf(bf2f(a.x)*c1.x - bf2f(b.x)*s1.x);
    o1.y = f2bf(bf2f(a.y)*c1.y - bf2f(b.y)*s1.y);
    o1.z = f2bf(bf2f(a.z)*c1.z - bf2f(b.z)*s1.z);
    o1.w = f2bf(bf2f(a.w)*c1.w - bf2f(b.w)*s1.w);
    o2.x = f2bf(bf2f(b.x)*c2.x + bf2f(a.x)*s2.x);
    o2.y = f2bf(bf2f(b.y)*c2.y + bf2f(a.y)*s2.y);
    o2.z = f2bf(bf2f(b.z)*c2.z + bf2f(a.z)*s2.z);
    o2.w = f2bf(bf2f(b.w)*c2.w + bf2f(a.w)*s2.w);
    *(ushort4*)base = o1;
    *(ushort4*)(base + 64) = o2;
  }
  {
    const int head = t >> 5;
    const int d0 = (t & 31) << 1;
    u16* base = k + row * (NKV * HD) + head * HD + d0;
    ushort2 a = *(const ushort2*)base;
    ushort2 b = *(const ushort2*)(base + 64);
    float2 c1 = *(const float2*)(cr + d0);
    float2 s1 = *(const float2*)(sr + d0);
    float2 c2 = *(const float2*)(cr + 64 + d0);
    float2 s2 = *(const float2*)(sr + 64 + d0);
    ushort2 o1, o2;
    o1.x = f2bf(bf2f(a.x)*c1.x - bf2f(b.x)*s1.x);
    o1.y = f2bf(bf2f(a.y)*c1.y - bf2f(b.y)*s1.y);
    o2.x = f2bf(bf2f(b.x)*c2.x + bf2f(a.x)*s2.x);
    o2.y = f2bf(bf2f(b.y)*c2.y + bf2f(a.y)*s2.y);
    *(ushort2*)base = o1;
    *(ushort2*)(base + 64) = o2;
  }
}

// ---------------- sliding-window attention (masked-fragment skip + setprio) ----------
__global__ __launch_bounds__(512) void attn_sw(const u16* __restrict__ q,
    const u16* __restrict__ k, const u16* __restrict__ v, u16* __restrict__ o)
{
  extern __shared__ u16 smem[];
  u16* kv0  = smem;               // 2 * 16384 u16 = 64KB
  u16* pbuf = smem + 2 * 16384;   // 8 * 4096 u16 = 64KB

  const int qb = blockIdx.x, h = blockIdx.y, b = blockIdx.z;
  const int kvh = h >> 1;
  const int tid = threadIdx.x, l = tid & 63, w = tid >> 6;
  const int lr = l & 15, lc = l >> 4;
  const int t0 = (qb == 0) ? 1 : 0;
  const int q0 = qb * 128;
  const int kst = NKV * HD;       // 1024

#pragma unroll
  for (int t = 0; t < 2; ++t){
    if (t >= t0){
      const int kb = qb - 1 + t;
      const u16* kbase = k + (b * NL + kb * 128) * kst + kvh * HD;
#pragma unroll
      for (int c = 0; c < 4; ++c){
        int off = c * 8192 + tid * 16;
        int row = off >> 8;
        int ch  = (off >> 4) & 15;
        int gch = ch ^ (row & 7);
        gld_lds16(kbase + row * kst + gch * 8, kv0 + t * 16384 + (off >> 1));
      }
    }
  }

  bf16x8 aq[4];
  {
    const int qrow = b * NL + q0 + w * 16 + lr;
#pragma unroll
    for (int kc = 0; kc < 4; ++kc)
      aq[kc] = *(const bf16x8*)(q + qrow * (NH * HD) + h * HD + kc * 32 + lc * 8);
  }
  __syncthreads();

  f32x4 sc[2][8] = {};
  __builtin_amdgcn_s_setprio(1);
#pragma unroll
  for (int t = 0; t < 2; ++t){
#pragma unroll
    for (int cb = 0; cb < 8; ++cb){
      const bool live = (t == 0) ? (t0 == 0 && cb >= w) : (cb <= w);
      if (live){
        f32x4 a = {};
#pragma unroll
        for (int kc = 0; kc < 4; ++kc){
          int row = cb * 16 + lr;
          bf16x8 bk = *(const bf16x8*)(kv0 + t * 16384 +
              ((row * 256 + ((kc * 64 + lc * 16) ^ ((row & 7) << 4))) >> 1));
          a = __builtin_amdgcn_mfma_f32_16x16x32_bf16(aq[kc], bk, a, 0, 0, 0);
        }
        sc[t][cb] = a;
      }
    }
  }
  __builtin_amdgcn_s_setprio(0);

  const float scale = 0.08838834764831845f;
  float mx[4] = {-3e38f, -3e38f, -3e38f, -3e38f};
#pragma unroll
  for (int t = 0; t < 2; ++t)
#pragma unroll
    for (int cb = 0; cb < 8; ++cb){
      const bool liveF = (t == 0) ? (t0 == 0 && cb >= w) : (cb <= w);
      if (liveF){
#pragma unroll
        for (int r = 0; r < 4; ++r){
          int rbl = w * 16 + lc * 4 + r;
          int c = cb * 16 + lr;
          bool keep = (t == 0) ? (c >= rbl) : (c <= rbl);
          float val = keep ? sc[t][cb][r] * scale : -1e30f;
          sc[t][cb][r] = val;
          mx[r] = fmaxf(mx[r], val);
        }
      }
    }
#pragma unroll
  for (int r = 0; r < 4; ++r){
    mx[r] = fmaxf(mx[r], __shfl_xor(mx[r], 1));
    mx[r] = fmaxf(mx[r], __shfl_xor(mx[r], 2));
    mx[r] = fmaxf(mx[r], __shfl_xor(mx[r], 4));
    mx[r] = fmaxf(mx[r], __shfl_xor(mx[r], 8));
  }

  float sm[4] = {0.f, 0.f, 0.f, 0.f};
  u16* pw = pbuf + w * 4096;
#pragma unroll
  for (int t = 0; t < 2; ++t)
#pragma unroll
    for (int cb = 0; cb < 8; ++cb){
      const bool liveC = (t == 0) ? (t0 == 0 && cb >= w) : (cb <= w);
      const bool readN = (t == 0) ? (t0 == 0 && (cb | 1) >= w) : ((cb & ~1) <= w);
      if (liveC){
#pragma unroll
        for (int r = 0; r < 4; ++r){
          float p = __expf(sc[t][cb][r] - mx[r]);
          sm[r] += p;
          int rr = lc * 4 + r;
          int colb = (t * 128 + cb * 16 + lr) * 2;
          pw[((rr * 512 + colb) ^ ((rr & 7) << 4)) >> 1] = f2bf(p);
        }
      } else if (readN){
#pragma unroll
        for (int r = 0; r < 4; ++r){
          int rr = lc * 4 + r;
          int colb = (t * 128 + cb * 16 + lr) * 2;
          pw[((rr * 512 + colb) ^ ((rr & 7) << 4)) >> 1] = 0;
        }
      }
    }
#pragma unroll
  for (int r = 0; r < 4; ++r){
    sm[r] += __shfl_xor(sm[r], 1);
    sm[r] += __shfl_xor(sm[r], 2);
    sm[r] += __shfl_xor(sm[r], 4);
    sm[r] += __shfl_xor(sm[r], 8);
  }

  __syncthreads();

  {
    const int key = tid & 127;
    const int h2 = tid >> 7;
#pragma unroll
    for (int t = 0; t < 2; ++t){
      if (t >= t0){
        const int kb = qb - 1 + t;
        const u16* vbase = v + (b * NL + kb * 128 + key) * kst + kvh * HD + h2 * 32;
        u16* dst = kv0 + t * 16384;
#pragma unroll
        for (int c2 = 0; c2 < 4; ++c2){
          union { uint4 v4; u16 s[8]; } u;
          u.v4 = *(const uint4*)(vbase + c2 * 8);
          int d0 = h2 * 32 + c2 * 8;
#pragma unroll
          for (int e = 0; e < 8; ++e){
            int d = d0 + e;
            dst[((d * 256 + key * 2) ^ ((d & 7) << 4)) >> 1] = u.s[e];
          }
        }
      }
    }
  }
  __syncthreads();

  f32x4 od[8] = {};
  __builtin_amdgcn_s_setprio(1);
#pragma unroll
  for (int kc = 0; kc < 8; ++kc){
    const int t = kc >> 2, kl = kc & 3;
    const bool live = (t == 0) ? (t0 == 0 && (kl * 2 + 1) >= w) : (kl * 2 <= w);
    if (live){
      int abyte = ((lr * 512 + (kc * 32 + lc * 8) * 2) ^ ((lr & 7) << 4));
      bf16x8 pa = *(const bf16x8*)(pbuf + w * 4096 + (abyte >> 1));
#pragma unroll
      for (int cb = 0; cb < 8; ++cb){
        int d = cb * 16 + lr;
        bf16x8 vb = *(const bf16x8*)(kv0 + t * 16384 +
            ((d * 256 + ((kl * 64 + lc * 16) ^ ((d & 7) << 4))) >> 1));
        od[cb] = __builtin_amdgcn_mfma_f32_16x16x32_bf16(pa, vb, od[cb], 0, 0, 0);
      }
    }
  }
  __builtin_amdgcn_s_setprio(0);

  float inv[4];
#pragma unroll
  for (int r = 0; r < 4; ++r) inv[r] = 1.0f / sm[r];
#pragma unroll
  for (int cb = 0; cb < 8; ++cb)
#pragma unroll
    for (int r = 0; r < 4; ++r){
      int orow = b * NL + q0 + w * 16 + lc * 4 + r;
      int ocol = h * HD + cb * 16 + lr;
      o[orow * (NH * HD) + ocol] = f2bf(od[cb][r] * inv[r]);
    }
}

// ---------------- launcher ----------------
extern "C" void kernel_launch(void* const* d_in, const int* in_sizes, int n_in,
                              void* d_out, int out_size, void* d_ws, size_t ws_size,
                              hipStream_t stream)
{
  const float* x    = (const float*)d_in[0];
  const float* cosb = (const float*)d_in[1];
  const float* sinb = (const float*)d_in[2];
  const float* wq   = (const float*)d_in[3];
  const float* wk   = (const float*)d_in[4];
  const float* wv   = (const float*)d_in[5];
  const float* wo   = (const float*)d_in[6];

  u16* p = (u16*)d_ws;
  u16* xb   = p; p += NB * NL * NDIM;
  u16* wqkv = p; p += (NH + 2 * NKV) * HD * NDIM;   // wq|wk|wv contiguous
  u16* wob  = p; p += NDIM * NH * HD;
  u16* qb   = p; p += NB * NL * NH * HD;
  u16* kb   = p; p += NB * NL * NKV * HD;
  u16* vb   = p; p += NB * NL * NKV * HD;
  u16* ab   = p; p += NB * NL * NH * HD;

  cast_all<<<2048, 256, 0, stream>>>(x, wq, wk, wv, wo, xb);

  hipFuncSetAttribute(reinterpret_cast<const void*>(gemm8p<2>),
                      hipFuncAttributeMaxDynamicSharedMemorySize, 131072);
  hipFuncSetAttribute(reinterpret_cast<const void*>(gemm8p<0>),
                      hipFuncAttributeMaxDynamicSharedMemorySize, 131072);
  hipFuncSetAttribute(reinterpret_cast<const void*>(attn_sw),
                      hipFuncAttributeMaxDynamicSharedMemorySize, 131072);

  // fused QKV projection: M=4096, N=4096, K=2048
  gemm8p<2><<<dim3(16, 16), 512, 131072, stream>>>(xb, wqkv, qb, kb, vb,
                                                   NB * NL, (NH + 2 * NKV) * HD, NDIM);

  rope_kernel<<<NB * NL, 256, 0, stream>>>(qb, kb, cosb, sinb);

  attn_sw<<<dim3(NL / 128, NH, NB), 512, 131072, stream>>>(qb, kb, vb, ab);

  // output projection: M=4096, N=2048, K=2048
  gemm8p<0><<<dim3(8, 16), 512, 131072, stream>>>(ab, wob, d_out, nullptr, nullptr,
                                                  NB * NL, NDIM, NH * HD);
}

// Round 4
// 278.036 us; speedup vs baseline: 1.3621x; 1.0501x over previous
//
#include <hip/hip_runtime.h>
#include <stdint.h>

#define NB 2
#define NL 2048
#define NDIM 2048
#define NH 16
#define NKV 8
#define HD 128

typedef unsigned short u16;
typedef unsigned int u32;
using f32x4 = __attribute__((ext_vector_type(4))) float;
using bf16x8 = __attribute__((ext_vector_type(8))) short;

__device__ __forceinline__ u16 f2bf(float f){
  union { float f; u32 u; } v; v.f = f;
  u32 r = v.u + 0x7fffu + ((v.u >> 16) & 1u);
  return (u16)(r >> 16);
}
__device__ __forceinline__ float bf2f(u16 u){
  union { u32 u; float f; } v; v.u = ((u32)u) << 16;
  return v.f;
}

__device__ __forceinline__ void gld_lds16(const void* g, void* l){
  __builtin_amdgcn_global_load_lds(
      (const __attribute__((address_space(1))) u32*)g,
      (__attribute__((address_space(3))) u32*)l, 16, 0, 0);
}

// ---------------- fused cast f32 -> bf16 (x, wq, wk, wv, wo -> contiguous ws) ---------
#define X4   (NB*NL*NDIM/4)
#define WQ4  (NH*HD*NDIM/4)
#define WK4  (NKV*HD*NDIM/4)
#define WV4  (NKV*HD*NDIM/4)
#define WO4  (NDIM*NH*HD/4)
#define TOT4 (X4+WQ4+WK4+WV4+WO4)

__global__ __launch_bounds__(256) void cast_all(const float* __restrict__ x,
    const float* __restrict__ wq, const float* __restrict__ wk,
    const float* __restrict__ wv, const float* __restrict__ wo,
    u16* __restrict__ dst)
{
  int i = blockIdx.x * blockDim.x + threadIdx.x;
  int stride = gridDim.x * blockDim.x;
  for (; i < TOT4; i += stride){
    const float* src; int off;
    if      (i < X4)                 { src = x;  off = i; }
    else if (i < X4+WQ4)             { src = wq; off = i - X4; }
    else if (i < X4+WQ4+WK4)         { src = wk; off = i - (X4+WQ4); }
    else if (i < X4+WQ4+WK4+WV4)     { src = wv; off = i - (X4+WQ4+WK4); }
    else                             { src = wo; off = i - (X4+WQ4+WK4+WV4); }
    float4 f = ((const float4*)src)[off];
    ushort4 o;
    o.x = f2bf(f.x); o.y = f2bf(f.y); o.z = f2bf(f.z); o.w = f2bf(f.w);
    ((ushort4*)dst)[i] = o;
  }
}

// ================= 256x256 8-phase GEMM, deep-prefetch schedule =================
// C(M,N) = A(M,K) @ Bw(N,K)^T. BM=BN=256, BK=64, 512 thr = 8 waves (2M x 4N).
// LDS 128KB dbuf. st_16x32 swizzle; gld_lds -> linear LDS, inverse-swizzled source.
// Region last-read map: A-h0@P2(wm0), A-h1@P2(wm1), B-h0@P1, B-h1@P1.
// Issue placement (all >= 8 phases before consumption):
//   P0: A-h1(u+1) -> buf[(u+1)&1] (free since P2 of u-1)
//   P2: B-h0(u+2) -> buf[u&1]     (free after P1 of u)
//   P3: A-h0(u+2), B-h1(u+2)      (free after P2 / P1 of u)
// Steady-state wait: vmcnt(6) (= 3 half-tiles in flight) once per K-tile.
template<int MODE>
__global__ __launch_bounds__(512, 2) void gemm8p(const u16* __restrict__ A,
    const u16* __restrict__ Bw, void* __restrict__ Cp, u16* __restrict__ ko,
    u16* __restrict__ vo, int M, int N, int K)
{
  extern __shared__ char lds[];
  const int tid = threadIdx.x;
  const int l = tid & 63, w = tid >> 6;
  const int wm = w >> 2, wn = w & 3;        // wave grid 2 x 4
  const int r = l & 15, cq = l >> 4;
  const int m0 = blockIdx.y << 8, n0 = blockIdx.x << 8;
  const int T = K >> 6;

  const int laneOff = (r * 64 + cq * 16) ^ ((r & 8) << 2);

  int stL[4];
  const u16* gA[4]; const u16* gB[4];
#pragma unroll
  for (int h = 0; h < 2; ++h)
#pragma unroll
    for (int g = 0; g < 2; ++g){
      int idx = h * 2 + g;
      int L = h * 16384 + (g * 512 + tid) * 16;
      int s  = L >> 10;
      int rr = (L >> 6) & 15;
      int c2 = (L & 63) ^ ((rr & 8) << 2);
      int row = ((s >> 1) << 4) | rr;
      int col = ((s & 1) << 5) | (c2 >> 1);
      stL[idx] = L;
      gA[idx] = A  + (size_t)(m0 + row) * K + col;
      gB[idx] = Bw + (size_t)(n0 + row) * K + col;
    }

#define ISSUE_A(h, v) do { if ((v) < T){ int _b = ((v) & 1) << 16;            \
    gld_lds16(gA[(h)*2+0] + (v)*64, lds + _b + stL[(h)*2+0]);                 \
    gld_lds16(gA[(h)*2+1] + (v)*64, lds + _b + stL[(h)*2+1]); } } while(0)
#define ISSUE_B(h, v) do { if ((v) < T){ int _b = (((v) & 1) << 16) + 32768;  \
    gld_lds16(gB[(h)*2+0] + (v)*64, lds + _b + stL[(h)*2+0]);                 \
    gld_lds16(gB[(h)*2+1] + (v)*64, lds + _b + stL[(h)*2+1]); } } while(0)

#define LDA(mi, kk) (*(const bf16x8*)(lds + bb + ((((wm*8+(mi))*2+(kk))) << 10) + laneOff))
#define LDB(ni, kk) (*(const bf16x8*)(lds + bb + 32768 + ((((wn*4+(ni))*2+(kk))) << 10) + laneOff))

#define BAR()    __builtin_amdgcn_s_barrier()
#define LGKM0()  do { asm volatile("s_waitcnt lgkmcnt(0)" ::: "memory"); \
                      __builtin_amdgcn_sched_barrier(0); } while(0)

  // ---- prologue: tile0 complete, then 3 halves of tile1 (A-h1(1) comes at P0 of u=0)
  ISSUE_A(0, 0); ISSUE_A(1, 0); ISSUE_B(0, 0); ISSUE_B(1, 0);
  ISSUE_B(0, 1); ISSUE_A(0, 1); ISSUE_B(1, 1);
  asm volatile("s_waitcnt vmcnt(6)" ::: "memory");   // tile0 landed
  BAR();

  f32x4 acc[8][4] = {};
  bf16x8 av[4][2], bv[4][2];

#pragma unroll 2
  for (int u = 0; u < T; ++u){
    const int bb = (u & 1) << 16;
    // ---------- P0 ----------
#pragma unroll
    for (int mi = 0; mi < 4; ++mi){ av[mi][0] = LDA(mi, 0); av[mi][1] = LDA(mi, 1); }
#pragma unroll
    for (int ni = 0; ni < 2; ++ni){ bv[ni][0] = LDB(ni, 0); bv[ni][1] = LDB(ni, 1); }
    ISSUE_A(1, u + 1);
    BAR(); LGKM0();
    __builtin_amdgcn_s_setprio(1);
#pragma unroll
    for (int kk = 0; kk < 2; ++kk)
#pragma unroll
      for (int mi = 0; mi < 4; ++mi)
#pragma unroll
        for (int ni = 0; ni < 2; ++ni)
          acc[mi][ni] = __builtin_amdgcn_mfma_f32_16x16x32_bf16(av[mi][kk], bv[ni][kk], acc[mi][ni], 0, 0, 0);
    __builtin_amdgcn_s_setprio(0);
    BAR();
    // ---------- P1 ----------
#pragma unroll
    for (int ni = 2; ni < 4; ++ni){ bv[ni][0] = LDB(ni, 0); bv[ni][1] = LDB(ni, 1); }
    BAR(); LGKM0();
    __builtin_amdgcn_s_setprio(1);
#pragma unroll
    for (int kk = 0; kk < 2; ++kk)
#pragma unroll
      for (int mi = 0; mi < 4; ++mi)
#pragma unroll
        for (int ni = 2; ni < 4; ++ni)
          acc[mi][ni] = __builtin_amdgcn_mfma_f32_16x16x32_bf16(av[mi][kk], bv[ni][kk], acc[mi][ni], 0, 0, 0);
    __builtin_amdgcn_s_setprio(0);
    BAR();
    // ---------- P2 ----------
#pragma unroll
    for (int mi = 0; mi < 4; ++mi){ av[mi][0] = LDA(mi + 4, 0); av[mi][1] = LDA(mi + 4, 1); }
    ISSUE_B(0, u + 2);
    BAR(); LGKM0();
    __builtin_amdgcn_s_setprio(1);
#pragma unroll
    for (int kk = 0; kk < 2; ++kk)
#pragma unroll
      for (int mi = 0; mi < 4; ++mi)
#pragma unroll
        for (int ni = 0; ni < 2; ++ni)
          acc[mi + 4][ni] = __builtin_amdgcn_mfma_f32_16x16x32_bf16(av[mi][kk], bv[ni][kk], acc[mi + 4][ni], 0, 0, 0);
    __builtin_amdgcn_s_setprio(0);
    BAR();
    // ---------- P3 (no ds_reads, no pre-barrier: MFMA deps are register-only) ------
    ISSUE_A(0, u + 2);
    ISSUE_B(1, u + 2);
    __builtin_amdgcn_s_setprio(1);
#pragma unroll
    for (int kk = 0; kk < 2; ++kk)
#pragma unroll
      for (int mi = 0; mi < 4; ++mi)
#pragma unroll
        for (int ni = 2; ni < 4; ++ni)
          acc[mi + 4][ni] = __builtin_amdgcn_mfma_f32_16x16x32_bf16(av[mi][kk], bv[ni][kk], acc[mi + 4][ni], 0, 0, 0);
    __builtin_amdgcn_s_setprio(0);
    if (u + 2 < T) asm volatile("s_waitcnt vmcnt(6)" ::: "memory");
    else           asm volatile("s_waitcnt vmcnt(0)" ::: "memory");
    BAR();
  }

  // ---- epilogue: C/D layout col=lane&15, row=(lane>>4)*4+reg (m89-verified) ----
#pragma unroll
  for (int mi = 0; mi < 8; ++mi)
#pragma unroll
    for (int ni = 0; ni < 4; ++ni){
      const int colg = n0 + wn * 64 + ni * 16 + r;
#pragma unroll
      for (int rg = 0; rg < 4; ++rg){
        const int row = m0 + wm * 128 + mi * 16 + cq * 4 + rg;
        if (MODE == 0){
          ((float*)Cp)[(size_t)row * N + colg] = acc[mi][ni][rg];
        } else {
          u16 val = f2bf(acc[mi][ni][rg]);
          if (colg < 2048)      ((u16*)Cp)[row * 2048 + colg] = val;
          else if (colg < 3072) ko[row * 1024 + (colg - 2048)] = val;
          else                  vo[row * 1024 + (colg - 3072)] = val;
        }
      }
    }
#undef ISSUE_A
#undef ISSUE_B
#undef LDA
#undef LDB
}

// ================= 128x256 2-phase GEMM for wo (full-chip grid) =================
// C(M,N) f32 = A(M,K) @ Bw(N,K)^T. BM=128, BN=256, BK=64. 512 thr, waves 2M x 4N,
// per-wave 64x64 (mi0-3, ni0-3). LDS: B 3 bufs x 32KB (0..96KB), A 2 bufs x 16KB
// (98304+). 3-buffer B => no same-region write hazards; all issues at Ph1.
// Steady in-flight = tiles u+1,u+2 (6 halves... 6 instr kept) -> vmcnt(6).
__global__ __launch_bounds__(512, 2) void gemmWo(const u16* __restrict__ A,
    const u16* __restrict__ Bw, float* __restrict__ Cp, int M, int N, int K)
{
  extern __shared__ char lds[];
  const int tid = threadIdx.x;
  const int l = tid & 63, w = tid >> 6;
  const int wm = w >> 2, wn = w & 3;
  const int r = l & 15, cq = l >> 4;
  const int m0 = blockIdx.y << 7, n0 = blockIdx.x << 8;
  const int T = K >> 6;

  const int laneOff = (r * 64 + cq * 16) ^ ((r & 8) << 2);

  int stg[2];
  const u16* gWA[2]; const u16* gWB[4];
#pragma unroll
  for (int g = 0; g < 2; ++g){
    stg[g] = (g * 512 + tid) * 16;
    int L = stg[g];
    int s  = L >> 10;
    int rr = (L >> 6) & 15;
    int c2 = (L & 63) ^ ((rr & 8) << 2);
    int row = ((s >> 1) << 4) | rr;
    int col = ((s & 1) << 5) | (c2 >> 1);
    gWA[g] = A + (size_t)(m0 + row) * K + col;
  }
#pragma unroll
  for (int h = 0; h < 2; ++h)
#pragma unroll
    for (int g = 0; g < 2; ++g){
      int L = h * 16384 + stg[g];
      int s  = L >> 10;
      int rr = (L >> 6) & 15;
      int c2 = (L & 63) ^ ((rr & 8) << 2);
      int row = ((s >> 1) << 4) | rr;
      int col = ((s & 1) << 5) | (c2 >> 1);
      gWB[h * 2 + g] = Bw + (size_t)(n0 + row) * K + col;
    }

#define WISSUE_A(v, ab) do { if ((v) < T){ char* _d = lds + 98304 + (ab) * 16384; \
    gld_lds16(gWA[0] + (v)*64, _d + stg[0]);                                      \
    gld_lds16(gWA[1] + (v)*64, _d + stg[1]); } } while(0)
#define WISSUE_B(h, v, b3) do { if ((v) < T){ char* _d = lds + (b3) * 32768 + (h) * 16384; \
    gld_lds16(gWB[(h)*2+0] + (v)*64, _d + stg[0]);                                         \
    gld_lds16(gWB[(h)*2+1] + (v)*64, _d + stg[1]); } } while(0)

#define WLDA(mi, kk) (*(const bf16x8*)(lds + 98304 + curA * 16384 + ((((wm*4+(mi))*2+(kk))) << 10) + laneOff))
#define WLDB(ni, kk) (*(const bf16x8*)(lds + curB * 32768 + ((((wn*4+(ni))*2+(kk))) << 10) + laneOff))

  // prologue: tile0 (6 instr) then tile1 (6 instr)
  WISSUE_A(0, 0); WISSUE_B(0, 0, 0); WISSUE_B(1, 0, 0);
  WISSUE_A(1, 1); WISSUE_B(0, 1, 1); WISSUE_B(1, 1, 1);
  asm volatile("s_waitcnt vmcnt(6)" ::: "memory");
  __builtin_amdgcn_s_barrier();

  f32x4 acc[4][4] = {};
  bf16x8 av[4][2], bv[4][2];
  int c0 = 0;   // u % 3

  for (int u = 0; u < T; ++u){
    const int curA = u & 1;
    const int curB = c0;
    const int c2i = (c0 + 2 >= 3) ? (c0 - 1) : (c0 + 2);   // (u+2) % 3
    // ---------- Ph0 ----------
#pragma unroll
    for (int mi = 0; mi < 4; ++mi){ av[mi][0] = WLDA(mi, 0); av[mi][1] = WLDA(mi, 1); }
#pragma unroll
    for (int ni = 0; ni < 2; ++ni){ bv[ni][0] = WLDB(ni, 0); bv[ni][1] = WLDB(ni, 1); }
    __builtin_amdgcn_s_barrier();
    asm volatile("s_waitcnt lgkmcnt(0)" ::: "memory");
    __builtin_amdgcn_sched_barrier(0);
    __builtin_amdgcn_s_setprio(1);
#pragma unroll
    for (int kk = 0; kk < 2; ++kk)
#pragma unroll
      for (int mi = 0; mi < 4; ++mi)
#pragma unroll
        for (int ni = 0; ni < 2; ++ni)
          acc[mi][ni] = __builtin_amdgcn_mfma_f32_16x16x32_bf16(av[mi][kk], bv[ni][kk], acc[mi][ni], 0, 0, 0);
    __builtin_amdgcn_s_setprio(0);
    __builtin_amdgcn_s_barrier();
    // ---------- Ph1 ----------
#pragma unroll
    for (int ni = 2; ni < 4; ++ni){ bv[ni][0] = WLDB(ni, 0); bv[ni][1] = WLDB(ni, 1); }
    WISSUE_A(u + 2, curA);            // A buf free after Ph0 (all waves barrier'd)
    WISSUE_B(0, u + 2, c2i);          // 3-buffer B: target idle buffer
    WISSUE_B(1, u + 2, c2i);
    __builtin_amdgcn_s_barrier();
    asm volatile("s_waitcnt lgkmcnt(0)" ::: "memory");
    __builtin_amdgcn_sched_barrier(0);
    __builtin_amdgcn_s_setprio(1);
#pragma unroll
    for (int kk = 0; kk < 2; ++kk)
#pragma unroll
      for (int mi = 0; mi < 4; ++mi)
#pragma unroll
        for (int ni = 2; ni < 4; ++ni)
          acc[mi][ni] = __builtin_amdgcn_mfma_f32_16x16x32_bf16(av[mi][kk], bv[ni][kk], acc[mi][ni], 0, 0, 0);
    __builtin_amdgcn_s_setprio(0);
    if (u + 2 < T) asm volatile("s_waitcnt vmcnt(6)" ::: "memory");
    else           asm volatile("s_waitcnt vmcnt(0)" ::: "memory");
    __builtin_amdgcn_s_barrier();
    c0 = (c0 == 2) ? 0 : (c0 + 1);
  }

#pragma unroll
  for (int mi = 0; mi < 4; ++mi)
#pragma unroll
    for (int ni = 0; ni < 4; ++ni){
      const int colg = n0 + wn * 64 + ni * 16 + r;
#pragma unroll
      for (int rg = 0; rg < 4; ++rg){
        const int row = m0 + wm * 64 + mi * 16 + cq * 4 + rg;
        Cp[(size_t)row * N + colg] = acc[mi][ni][rg];
      }
    }
#undef WISSUE_A
#undef WISSUE_B
#undef WLDA
#undef WLDB
}

// ---------------- RoPE (in-place, HF rotate_half) ----------------
__global__ __launch_bounds__(256) void rope_kernel(u16* __restrict__ q, u16* __restrict__ k,
    const float* __restrict__ cosb, const float* __restrict__ sinb)
{
  const int row = blockIdx.x;           // b*NL + l
  const int pos = row & (NL - 1);
  const float* cr = cosb + pos * HD;
  const float* sr = sinb + pos * HD;
  const int t = threadIdx.x;
  {
    const int head = t >> 4;
    const int d0 = (t & 15) << 2;
    u16* base = q + row * (NH * HD) + head * HD + d0;
    ushort4 a = *(const ushort4*)base;
    ushort4 b = *(const ushort4*)(base + 64);
    float4 c1 = *(const float4*)(cr + d0);
    float4 s1 = *(const float4*)(sr + d0);
    float4 c2 = *(const float4*)(cr + 64 + d0);
    float4 s2 = *(const float4*)(sr + 64 + d0);
    ushort4 o1, o2;
    o1.x = f2bf(bf2f(a.x)*c1.x - bf2f(b.x)*s1.x);
    o1.y = f2bf(bf2f(a.y)*c1.y - bf2f(b.y)*s1.y);
    o1.z = f2bf(bf2f(a.z)*c1.z - bf2f(b.z)*s1.z);
    o1.w = f2bf(bf2f(a.w)*c1.w - bf2f(b.w)*s1.w);
    o2.x = f2bf(bf2f(b.x)*c2.x + bf2f(a.x)*s2.x);
    o2.y = f2bf(bf2f(b.y)*c2.y + bf2f(a.y)*s2.y);
    o2.z = f2bf(bf2f(b.z)*c2.z + bf2f(a.z)*s2.z);
    o2.w = f2bf(bf2f(b.w)*c2.w + bf2f(a.w)*s2.w);
    *(ushort4*)base = o1;
    *(ushort4*)(base + 64) = o2;
  }
  {
    const int head = t >> 5;
    const int d0 = (t & 31) << 1;
    u16* base = k + row * (NKV * HD) + head * HD + d0;
    ushort2 a = *(const ushort2*)base;
    ushort2 b = *(const ushort2*)(base + 64);
    float2 c1 = *(const float2*)(cr + d0);
    float2 s1 = *(const float2*)(sr + d0);
    float2 c2 = *(const float2*)(cr + 64 + d0);
    float2 s2 = *(const float2*)(sr + 64 + d0);
    ushort2 o1, o2;
    o1.x = f2bf(bf2f(a.x)*c1.x - bf2f(b.x)*s1.x);
    o1.y = f2bf(bf2f(a.y)*c1.y - bf2f(b.y)*s1.y);
    o2.x = f2bf(bf2f(b.x)*c2.x + bf2f(a.x)*s2.x);
    o2.y = f2bf(bf2f(b.y)*c2.y + bf2f(a.y)*s2.y);
    *(ushort2*)base = o1;
    *(ushort2*)(base + 64) = o2;
  }
}

// ---------------- sliding-window attention (masked-fragment skip + setprio) ----------
__global__ __launch_bounds__(512) void attn_sw(const u16* __restrict__ q,
    const u16* __restrict__ k, const u16* __restrict__ v, u16* __restrict__ o)
{
  extern __shared__ u16 smem[];
  u16* kv0  = smem;               // 2 * 16384 u16 = 64KB
  u16* pbuf = smem + 2 * 16384;   // 8 * 4096 u16 = 64KB

  const int qb = blockIdx.x, h = blockIdx.y, b = blockIdx.z;
  const int kvh = h >> 1;
  const int tid = threadIdx.x, l = tid & 63, w = tid >> 6;
  const int lr = l & 15, lc = l >> 4;
  const int t0 = (qb == 0) ? 1 : 0;
  const int q0 = qb * 128;
  const int kst = NKV * HD;       // 1024

#pragma unroll
  for (int t = 0; t < 2; ++t){
    if (t >= t0){
      const int kb = qb - 1 + t;
      const u16* kbase = k + (b * NL + kb * 128) * kst + kvh * HD;
#pragma unroll
      for (int c = 0; c < 4; ++c){
        int off = c * 8192 + tid * 16;
        int row = off >> 8;
        int ch  = (off >> 4) & 15;
        int gch = ch ^ (row & 7);
        gld_lds16(kbase + row * kst + gch * 8, kv0 + t * 16384 + (off >> 1));
      }
    }
  }

  bf16x8 aq[4];
  {
    const int qrow = b * NL + q0 + w * 16 + lr;
#pragma unroll
    for (int kc = 0; kc < 4; ++kc)
      aq[kc] = *(const bf16x8*)(q + qrow * (NH * HD) + h * HD + kc * 32 + lc * 8);
  }
  __syncthreads();

  f32x4 sc[2][8] = {};
  __builtin_amdgcn_s_setprio(1);
#pragma unroll
  for (int t = 0; t < 2; ++t){
#pragma unroll
    for (int cb = 0; cb < 8; ++cb){
      const bool live = (t == 0) ? (t0 == 0 && cb >= w) : (cb <= w);
      if (live){
        f32x4 a = {};
#pragma unroll
        for (int kc = 0; kc < 4; ++kc){
          int row = cb * 16 + lr;
          bf16x8 bk = *(const bf16x8*)(kv0 + t * 16384 +
              ((row * 256 + ((kc * 64 + lc * 16) ^ ((row & 7) << 4))) >> 1));
          a = __builtin_amdgcn_mfma_f32_16x16x32_bf16(aq[kc], bk, a, 0, 0, 0);
        }
        sc[t][cb] = a;
      }
    }
  }
  __builtin_amdgcn_s_setprio(0);

  const float scale = 0.08838834764831845f;
  float mx[4] = {-3e38f, -3e38f, -3e38f, -3e38f};
#pragma unroll
  for (int t = 0; t < 2; ++t)
#pragma unroll
    for (int cb = 0; cb < 8; ++cb){
      const bool liveF = (t == 0) ? (t0 == 0 && cb >= w) : (cb <= w);
      if (liveF){
#pragma unroll
        for (int r = 0; r < 4; ++r){
          int rbl = w * 16 + lc * 4 + r;
          int c = cb * 16 + lr;
          bool keep = (t == 0) ? (c >= rbl) : (c <= rbl);
          float val = keep ? sc[t][cb][r] * scale : -1e30f;
          sc[t][cb][r] = val;
          mx[r] = fmaxf(mx[r], val);
        }
      }
    }
#pragma unroll
  for (int r = 0; r < 4; ++r){
    mx[r] = fmaxf(mx[r], __shfl_xor(mx[r], 1));
    mx[r] = fmaxf(mx[r], __shfl_xor(mx[r], 2));
    mx[r] = fmaxf(mx[r], __shfl_xor(mx[r], 4));
    mx[r] = fmaxf(mx[r], __shfl_xor(mx[r], 8));
  }

  float sm[4] = {0.f, 0.f, 0.f, 0.f};
  u16* pw = pbuf + w * 4096;
#pragma unroll
  for (int t = 0; t < 2; ++t)
#pragma unroll
    for (int cb = 0; cb < 8; ++cb){
      const bool liveC = (t == 0) ? (t0 == 0 && cb >= w) : (cb <= w);
      const bool readN = (t == 0) ? (t0 == 0 && (cb | 1) >= w) : ((cb & ~1) <= w);
      if (liveC){
#pragma unroll
        for (int r = 0; r < 4; ++r){
          float p = __expf(sc[t][cb][r] - mx[r]);
          sm[r] += p;
          int rr = lc * 4 + r;
          int colb = (t * 128 + cb * 16 + lr) * 2;
          pw[((rr * 512 + colb) ^ ((rr & 7) << 4)) >> 1] = f2bf(p);
        }
      } else if (readN){
#pragma unroll
        for (int r = 0; r < 4; ++r){
          int rr = lc * 4 + r;
          int colb = (t * 128 + cb * 16 + lr) * 2;
          pw[((rr * 512 + colb) ^ ((rr & 7) << 4)) >> 1] = 0;
        }
      }
    }
#pragma unroll
  for (int r = 0; r < 4; ++r){
    sm[r] += __shfl_xor(sm[r], 1);
    sm[r] += __shfl_xor(sm[r], 2);
    sm[r] += __shfl_xor(sm[r], 4);
    sm[r] += __shfl_xor(sm[r], 8);
  }

  __syncthreads();

  {
    const int key = tid & 127;
    const int h2 = tid >> 7;
#pragma unroll
    for (int t = 0; t < 2; ++t){
      if (t >= t0){
        const int kb = qb - 1 + t;
        const u16* vbase = v + (b * NL + kb * 128 + key) * kst + kvh * HD + h2 * 32;
        u16* dst = kv0 + t * 16384;
#pragma unroll
        for (int c2 = 0; c2 < 4; ++c2){
          union { uint4 v4; u16 s[8]; } u;
          u.v4 = *(const uint4*)(vbase + c2 * 8);
          int d0 = h2 * 32 + c2 * 8;
#pragma unroll
          for (int e = 0; e < 8; ++e){
            int d = d0 + e;
            dst[((d * 256 + key * 2) ^ ((d & 7) << 4)) >> 1] = u.s[e];
          }
        }
      }
    }
  }
  __syncthreads();

  f32x4 od[8] = {};
  __builtin_amdgcn_s_setprio(1);
#pragma unroll
  for (int kc = 0; kc < 8; ++kc){
    const int t = kc >> 2, kl = kc & 3;
    const bool live = (t == 0) ? (t0 == 0 && (kl * 2 + 1) >= w) : (kl * 2 <= w);
    if (live){
      int abyte = ((lr * 512 + (kc * 32 + lc * 8) * 2) ^ ((lr & 7) << 4));
      bf16x8 pa = *(const bf16x8*)(pbuf + w * 4096 + (abyte >> 1));
#pragma unroll
      for (int cb = 0; cb < 8; ++cb){
        int d = cb * 16 + lr;
        bf16x8 vb = *(const bf16x8*)(kv0 + t * 16384 +
            ((d * 256 + ((kl * 64 + lc * 16) ^ ((d & 7) << 4))) >> 1));
        od[cb] = __builtin_amdgcn_mfma_f32_16x16x32_bf16(pa, vb, od[cb], 0, 0, 0);
      }
    }
  }
  __builtin_amdgcn_s_setprio(0);

  float inv[4];
#pragma unroll
  for (int r = 0; r < 4; ++r) inv[r] = 1.0f / sm[r];
#pragma unroll
  for (int cb = 0; cb < 8; ++cb)
#pragma unroll
    for (int r = 0; r < 4; ++r){
      int orow = b * NL + q0 + w * 16 + lc * 4 + r;
      int ocol = h * HD + cb * 16 + lr;
      o[orow * (NH * HD) + ocol] = f2bf(od[cb][r] * inv[r]);
    }
}

// ---------------- launcher ----------------
extern "C" void kernel_launch(void* const* d_in, const int* in_sizes, int n_in,
                              void* d_out, int out_size, void* d_ws, size_t ws_size,
                              hipStream_t stream)
{
  const float* x    = (const float*)d_in[0];
  const float* cosb = (const float*)d_in[1];
  const float* sinb = (const float*)d_in[2];
  const float* wq   = (const float*)d_in[3];
  const float* wk   = (const float*)d_in[4];
  const float* wv   = (const float*)d_in[5];
  const float* wo   = (const float*)d_in[6];

  u16* p = (u16*)d_ws;
  u16* xb   = p; p += NB * NL * NDIM;
  u16* wqkv = p; p += (NH + 2 * NKV) * HD * NDIM;   // wq|wk|wv contiguous
  u16* wob  = p; p += NDIM * NH * HD;
  u16* qb   = p; p += NB * NL * NH * HD;
  u16* kb   = p; p += NB * NL * NKV * HD;
  u16* vb   = p; p += NB * NL * NKV * HD;
  u16* ab   = p; p += NB * NL * NH * HD;

  cast_all<<<2048, 256, 0, stream>>>(x, wq, wk, wv, wo, xb);

  hipFuncSetAttribute(reinterpret_cast<const void*>(gemm8p<2>),
                      hipFuncAttributeMaxDynamicSharedMemorySize, 131072);
  hipFuncSetAttribute(reinterpret_cast<const void*>(gemmWo),
                      hipFuncAttributeMaxDynamicSharedMemorySize, 131072);
  hipFuncSetAttribute(reinterpret_cast<const void*>(attn_sw),
                      hipFuncAttributeMaxDynamicSharedMemorySize, 131072);

  // fused QKV projection: M=4096, N=4096, K=2048
  gemm8p<2><<<dim3(16, 16), 512, 131072, stream>>>(xb, wqkv, qb, kb, vb,
                                                   NB * NL, (NH + 2 * NKV) * HD, NDIM);

  rope_kernel<<<NB * NL, 256, 0, stream>>>(qb, kb, cosb, sinb);

  attn_sw<<<dim3(NL / 128, NH, NB), 512, 131072, stream>>>(qb, kb, vb, ab);

  // output projection: M=4096, N=2048, K=2048 -> grid (8, 32) = 256 blocks
  gemmWo<<<dim3(8, 32), 512, 131072, stream>>>(ab, wob, (float*)d_out,
                                               NB * NL, NDIM, NH * HD);
}

// Round 5
// 261.993 us; speedup vs baseline: 1.4455x; 1.0612x over previous
//
#include <hip/hip_runtime.h>
#include <stdint.h>

#define NB 2
#define NL 2048
#define NDIM 2048
#define NH 16
#define NKV 8
#define HD 128

typedef unsigned short u16;
typedef unsigned int u32;
using f32x4 = __attribute__((ext_vector_type(4))) float;
using bf16x8 = __attribute__((ext_vector_type(8))) short;

__device__ __forceinline__ u16 f2bf(float f){
  union { float f; u32 u; } v; v.f = f;
  u32 r = v.u + 0x7fffu + ((v.u >> 16) & 1u);
  return (u16)(r >> 16);
}
__device__ __forceinline__ float bf2f(u16 u){
  union { u32 u; float f; } v; v.u = ((u32)u) << 16;
  return v.f;
}

__device__ __forceinline__ void gld_lds16(const void* g, void* l){
  __builtin_amdgcn_global_load_lds(
      (const __attribute__((address_space(1))) u32*)g,
      (__attribute__((address_space(3))) u32*)l, 16, 0, 0);
}

// ---------------- fused cast f32 -> bf16 (x, wq, wk, wv, wo -> contiguous ws) ---------
#define X4   (NB*NL*NDIM/4)
#define WQ4  (NH*HD*NDIM/4)
#define WK4  (NKV*HD*NDIM/4)
#define WV4  (NKV*HD*NDIM/4)
#define WO4  (NDIM*NH*HD/4)
#define TOT4 (X4+WQ4+WK4+WV4+WO4)

__global__ __launch_bounds__(256) void cast_all(const float* __restrict__ x,
    const float* __restrict__ wq, const float* __restrict__ wk,
    const float* __restrict__ wv, const float* __restrict__ wo,
    u16* __restrict__ dst)
{
  int i = blockIdx.x * blockDim.x + threadIdx.x;
  int stride = gridDim.x * blockDim.x;
  for (; i < TOT4; i += stride){
    const float* src; int off;
    if      (i < X4)                 { src = x;  off = i; }
    else if (i < X4+WQ4)             { src = wq; off = i - X4; }
    else if (i < X4+WQ4+WK4)         { src = wk; off = i - (X4+WQ4); }
    else if (i < X4+WQ4+WK4+WV4)     { src = wv; off = i - (X4+WQ4+WK4); }
    else                             { src = wo; off = i - (X4+WQ4+WK4+WV4); }
    float4 f = ((const float4*)src)[off];
    ushort4 o;
    o.x = f2bf(f.x); o.y = f2bf(f.y); o.z = f2bf(f.z); o.w = f2bf(f.w);
    ((ushort4*)dst)[i] = o;
  }
}

// ================= 256x256 GEMM, 3-barrier/K-tile pipelined schedule =================
// C(M,N) = A(M,K) @ Bw(N,K)^T. BM=BN=256, BK=64, 512 thr = 8 waves (2M x 4N).
// LDS 128KB dbuf, st_16x32 swizzle, gld_lds linear dest + inverse-swizzled source.
// Region map: A-h0 read by wm0 (phA mi0-3, phB mi4-7); A-h1 by wm1; B-h0 read by
// wn0/1 (all in phA); B-h1 by wn2/3 (phA).
// phA: {16 ds_read (av_lo + bv01 + bv23); ISSUE A-h1(u+1)->other buf; lgkm(4);
//       Q0; lgkm(0); Q1; BAR}
// phB: {8 ds_read (av_hi); ISSUE B-h0(u+2); lgkm(0); Q2; BAR}
// phC: {ISSUE A-h0,B-h1(u+2); Q3 (regs only); vmcnt(6|0); BAR}
// Race-freedom: every ISSUE's target region had all reads drained before a barrier
// that precedes the issue (issuer past BAR => all waves lgkm-waited those reads).
template<int MODE>
__global__ __launch_bounds__(512, 2) void gemm8p(const u16* __restrict__ A,
    const u16* __restrict__ Bw, void* __restrict__ Cp, u16* __restrict__ ko,
    u16* __restrict__ vo, int M, int N, int K)
{
  extern __shared__ char lds[];
  const int tid = threadIdx.x;
  const int l = tid & 63, w = tid >> 6;
  const int wm = w >> 2, wn = w & 3;        // wave grid 2 x 4
  const int r = l & 15, cq = l >> 4;
  const int m0 = blockIdx.y << 8, n0 = blockIdx.x << 8;
  const int T = K >> 6;

  const int laneOff = (r * 64 + cq * 16) ^ ((r & 8) << 2);

  int stL[4];
  const u16* gA[4]; const u16* gB[4];
#pragma unroll
  for (int h = 0; h < 2; ++h)
#pragma unroll
    for (int g = 0; g < 2; ++g){
      int idx = h * 2 + g;
      int L = h * 16384 + (g * 512 + tid) * 16;
      int s  = L >> 10;
      int rr = (L >> 6) & 15;
      int c2 = (L & 63) ^ ((rr & 8) << 2);
      int row = ((s >> 1) << 4) | rr;
      int col = ((s & 1) << 5) | (c2 >> 1);
      stL[idx] = L;
      gA[idx] = A  + (size_t)(m0 + row) * K + col;
      gB[idx] = Bw + (size_t)(n0 + row) * K + col;
    }

#define ISSUE_A(h, v) do { if ((v) < T){ int _b = ((v) & 1) << 16;            \
    gld_lds16(gA[(h)*2+0] + (v)*64, lds + _b + stL[(h)*2+0]);                 \
    gld_lds16(gA[(h)*2+1] + (v)*64, lds + _b + stL[(h)*2+1]); } } while(0)
#define ISSUE_B(h, v) do { if ((v) < T){ int _b = (((v) & 1) << 16) + 32768;  \
    gld_lds16(gB[(h)*2+0] + (v)*64, lds + _b + stL[(h)*2+0]);                 \
    gld_lds16(gB[(h)*2+1] + (v)*64, lds + _b + stL[(h)*2+1]); } } while(0)

#define LDA(mi, kk) (*(const bf16x8*)(lds + bb + ((((wm*8+(mi))*2+(kk))) << 10) + laneOff))
#define LDB(ni, kk) (*(const bf16x8*)(lds + bb + 32768 + ((((wn*4+(ni))*2+(kk))) << 10) + laneOff))

#define BAR()     __builtin_amdgcn_s_barrier()
#define LGKM(n)   do { asm volatile("s_waitcnt lgkmcnt(" #n ")" ::: "memory"); \
                       __builtin_amdgcn_sched_barrier(0); } while(0)

  // ---- prologue: tile0 complete (8) + B-h0,A-h0,B-h1 of tile1 (6) ----
  ISSUE_A(0, 0); ISSUE_A(1, 0); ISSUE_B(0, 0); ISSUE_B(1, 0);
  ISSUE_B(0, 1); ISSUE_A(0, 1); ISSUE_B(1, 1);
  asm volatile("s_waitcnt vmcnt(6)" ::: "memory");   // tile0 landed
  BAR();

  f32x4 acc[8][4] = {};
  bf16x8 av[4][2], bv[4][2];

#pragma unroll 2
  for (int u = 0; u < T; ++u){
    const int bb = (u & 1) << 16;
    // ---------- phase A: Q0 (ni0-1) + Q1 (ni2-3), all B reads + av_lo ----------
#pragma unroll
    for (int mi = 0; mi < 4; ++mi){ av[mi][0] = LDA(mi, 0); av[mi][1] = LDA(mi, 1); }
#pragma unroll
    for (int ni = 0; ni < 2; ++ni){ bv[ni][0] = LDB(ni, 0); bv[ni][1] = LDB(ni, 1); }
#pragma unroll
    for (int ni = 2; ni < 4; ++ni){ bv[ni][0] = LDB(ni, 0); bv[ni][1] = LDB(ni, 1); }
    ISSUE_A(1, u + 1);
    LGKM(4);                       // av_lo + bv01 ready; bv23 in flight under Q0
    __builtin_amdgcn_s_setprio(1);
#pragma unroll
    for (int kk = 0; kk < 2; ++kk)
#pragma unroll
      for (int mi = 0; mi < 4; ++mi)
#pragma unroll
        for (int ni = 0; ni < 2; ++ni)
          acc[mi][ni] = __builtin_amdgcn_mfma_f32_16x16x32_bf16(av[mi][kk], bv[ni][kk], acc[mi][ni], 0, 0, 0);
    __builtin_amdgcn_s_setprio(0);
    LGKM(0);                       // bv23 ready
    __builtin_amdgcn_s_setprio(1);
#pragma unroll
    for (int kk = 0; kk < 2; ++kk)
#pragma unroll
      for (int mi = 0; mi < 4; ++mi)
#pragma unroll
        for (int ni = 2; ni < 4; ++ni)
          acc[mi][ni] = __builtin_amdgcn_mfma_f32_16x16x32_bf16(av[mi][kk], bv[ni][kk], acc[mi][ni], 0, 0, 0);
    __builtin_amdgcn_s_setprio(0);
    BAR();
    // ---------- phase B: Q2 (mi4-7, ni0-1), av_hi reads ----------
#pragma unroll
    for (int mi = 0; mi < 4; ++mi){ av[mi][0] = LDA(mi + 4, 0); av[mi][1] = LDA(mi + 4, 1); }
    ISSUE_B(0, u + 2);
    LGKM(0);
    __builtin_amdgcn_s_setprio(1);
#pragma unroll
    for (int kk = 0; kk < 2; ++kk)
#pragma unroll
      for (int mi = 0; mi < 4; ++mi)
#pragma unroll
        for (int ni = 0; ni < 2; ++ni)
          acc[mi + 4][ni] = __builtin_amdgcn_mfma_f32_16x16x32_bf16(av[mi][kk], bv[ni][kk], acc[mi + 4][ni], 0, 0, 0);
    __builtin_amdgcn_s_setprio(0);
    BAR();
    // ---------- phase C: Q3 (mi4-7, ni2-3), register-only ----------
    ISSUE_A(0, u + 2);
    ISSUE_B(1, u + 2);
    __builtin_amdgcn_s_setprio(1);
#pragma unroll
    for (int kk = 0; kk < 2; ++kk)
#pragma unroll
      for (int mi = 0; mi < 4; ++mi)
#pragma unroll
        for (int ni = 2; ni < 4; ++ni)
          acc[mi + 4][ni] = __builtin_amdgcn_mfma_f32_16x16x32_bf16(av[mi][kk], bv[ni][kk], acc[mi + 4][ni], 0, 0, 0);
    __builtin_amdgcn_s_setprio(0);
    if (u + 2 < T) asm volatile("s_waitcnt vmcnt(6)" ::: "memory");
    else           asm volatile("s_waitcnt vmcnt(0)" ::: "memory");
    BAR();
  }

  // ---- epilogue: C/D layout col=lane&15, row=(lane>>4)*4+reg (m89-verified) ----
#pragma unroll
  for (int mi = 0; mi < 8; ++mi)
#pragma unroll
    for (int ni = 0; ni < 4; ++ni){
      const int colg = n0 + wn * 64 + ni * 16 + r;
#pragma unroll
      for (int rg = 0; rg < 4; ++rg){
        const int row = m0 + wm * 128 + mi * 16 + cq * 4 + rg;
        if (MODE == 0){
          ((float*)Cp)[(size_t)row * N + colg] = acc[mi][ni][rg];
        } else {
          u16 val = f2bf(acc[mi][ni][rg]);
          if (colg < 2048)      ((u16*)Cp)[row * 2048 + colg] = val;
          else if (colg < 3072) ko[row * 1024 + (colg - 2048)] = val;
          else                  vo[row * 1024 + (colg - 3072)] = val;
        }
      }
    }
#undef ISSUE_A
#undef ISSUE_B
#undef LDA
#undef LDB
}

// ================= 128x256 GEMM for wo, 2-barrier/K-tile =================
// BM=128, BN=256, BK=64, 512 thr, waves 2M x 4N, per-wave 64x64. LDS: B 3 bufs x
// 32KB (0..96KB), A 2 bufs x 16KB (98304+). A-tile read fully in PhA (av mi0-3 is
// the whole per-wave A need? no: av 8 reads = all 4 mi x 2 kk); B read fully in PhA.
// PhA: {16 reads; lgkm(4); MFMA ni01; BAR}
// PhB: {ISSUE A(u+2)->curA, B(u+2)->c2i; lgkm(0); MFMA ni23; vmcnt(6|0); BAR}
__global__ __launch_bounds__(512, 2) void gemmWo(const u16* __restrict__ A,
    const u16* __restrict__ Bw, float* __restrict__ Cp, int M, int N, int K)
{
  extern __shared__ char lds[];
  const int tid = threadIdx.x;
  const int l = tid & 63, w = tid >> 6;
  const int wm = w >> 2, wn = w & 3;
  const int r = l & 15, cq = l >> 4;
  const int m0 = blockIdx.y << 7, n0 = blockIdx.x << 8;
  const int T = K >> 6;

  const int laneOff = (r * 64 + cq * 16) ^ ((r & 8) << 2);

  int stg[2];
  const u16* gWA[2]; const u16* gWB[4];
#pragma unroll
  for (int g = 0; g < 2; ++g){
    stg[g] = (g * 512 + tid) * 16;
    int L = stg[g];
    int s  = L >> 10;
    int rr = (L >> 6) & 15;
    int c2 = (L & 63) ^ ((rr & 8) << 2);
    int row = ((s >> 1) << 4) | rr;
    int col = ((s & 1) << 5) | (c2 >> 1);
    gWA[g] = A + (size_t)(m0 + row) * K + col;
  }
#pragma unroll
  for (int h = 0; h < 2; ++h)
#pragma unroll
    for (int g = 0; g < 2; ++g){
      int L = h * 16384 + stg[g];
      int s  = L >> 10;
      int rr = (L >> 6) & 15;
      int c2 = (L & 63) ^ ((rr & 8) << 2);
      int row = ((s >> 1) << 4) | rr;
      int col = ((s & 1) << 5) | (c2 >> 1);
      gWB[h * 2 + g] = Bw + (size_t)(n0 + row) * K + col;
    }

#define WISSUE_A(v, ab) do { if ((v) < T){ char* _d = lds + 98304 + (ab) * 16384; \
    gld_lds16(gWA[0] + (v)*64, _d + stg[0]);                                      \
    gld_lds16(gWA[1] + (v)*64, _d + stg[1]); } } while(0)
#define WISSUE_B(h, v, b3) do { if ((v) < T){ char* _d = lds + (b3) * 32768 + (h) * 16384; \
    gld_lds16(gWB[(h)*2+0] + (v)*64, _d + stg[0]);                                         \
    gld_lds16(gWB[(h)*2+1] + (v)*64, _d + stg[1]); } } while(0)

#define WLDA(mi, kk) (*(const bf16x8*)(lds + 98304 + curA * 16384 + ((((wm*4+(mi))*2+(kk))) << 10) + laneOff))
#define WLDB(ni, kk) (*(const bf16x8*)(lds + curB * 32768 + ((((wn*4+(ni))*2+(kk))) << 10) + laneOff))

  // prologue: tile0 (6 instr) then tile1 (6 instr)
  WISSUE_A(0, 0); WISSUE_B(0, 0, 0); WISSUE_B(1, 0, 0);
  WISSUE_A(1, 1); WISSUE_B(0, 1, 1); WISSUE_B(1, 1, 1);
  asm volatile("s_waitcnt vmcnt(6)" ::: "memory");
  __builtin_amdgcn_s_barrier();

  f32x4 acc[4][4] = {};
  bf16x8 av[4][2], bv[4][2];
  int c0 = 0;   // u % 3

  for (int u = 0; u < T; ++u){
    const int curA = u & 1;
    const int curB = c0;
    const int c2i = (c0 + 2 >= 3) ? (c0 - 1) : (c0 + 2);   // (u+2) % 3
    // ---------- PhA: all 16 reads; MFMA ni0-1 ----------
#pragma unroll
    for (int mi = 0; mi < 4; ++mi){ av[mi][0] = WLDA(mi, 0); av[mi][1] = WLDA(mi, 1); }
#pragma unroll
    for (int ni = 0; ni < 2; ++ni){ bv[ni][0] = WLDB(ni, 0); bv[ni][1] = WLDB(ni, 1); }
#pragma unroll
    for (int ni = 2; ni < 4; ++ni){ bv[ni][0] = WLDB(ni, 0); bv[ni][1] = WLDB(ni, 1); }
    asm volatile("s_waitcnt lgkmcnt(4)" ::: "memory");
    __builtin_amdgcn_sched_barrier(0);
    __builtin_amdgcn_s_setprio(1);
#pragma unroll
    for (int kk = 0; kk < 2; ++kk)
#pragma unroll
      for (int mi = 0; mi < 4; ++mi)
#pragma unroll
        for (int ni = 0; ni < 2; ++ni)
          acc[mi][ni] = __builtin_amdgcn_mfma_f32_16x16x32_bf16(av[mi][kk], bv[ni][kk], acc[mi][ni], 0, 0, 0);
    __builtin_amdgcn_s_setprio(0);
    __builtin_amdgcn_s_barrier();
    // ---------- PhB: issues; MFMA ni2-3 ----------
    WISSUE_A(u + 2, curA);
    WISSUE_B(0, u + 2, c2i);
    WISSUE_B(1, u + 2, c2i);
    asm volatile("s_waitcnt lgkmcnt(0)" ::: "memory");
    __builtin_amdgcn_sched_barrier(0);
    __builtin_amdgcn_s_setprio(1);
#pragma unroll
    for (int kk = 0; kk < 2; ++kk)
#pragma unroll
      for (int mi = 0; mi < 4; ++mi)
#pragma unroll
        for (int ni = 2; ni < 4; ++ni)
          acc[mi][ni] = __builtin_amdgcn_mfma_f32_16x16x32_bf16(av[mi][kk], bv[ni][kk], acc[mi][ni], 0, 0, 0);
    __builtin_amdgcn_s_setprio(0);
    if (u + 2 < T) asm volatile("s_waitcnt vmcnt(6)" ::: "memory");
    else           asm volatile("s_waitcnt vmcnt(0)" ::: "memory");
    __builtin_amdgcn_s_barrier();
    c0 = (c0 == 2) ? 0 : (c0 + 1);
  }

#pragma unroll
  for (int mi = 0; mi < 4; ++mi)
#pragma unroll
    for (int ni = 0; ni < 4; ++ni){
      const int colg = n0 + wn * 64 + ni * 16 + r;
#pragma unroll
      for (int rg = 0; rg < 4; ++rg){
        const int row = m0 + wm * 64 + mi * 16 + cq * 4 + rg;
        Cp[(size_t)row * N + colg] = acc[mi][ni][rg];
      }
    }
#undef WISSUE_A
#undef WISSUE_B
#undef WLDA
#undef WLDB
}

// ---------------- RoPE (in-place, HF rotate_half) ----------------
__global__ __launch_bounds__(256) void rope_kernel(u16* __restrict__ q, u16* __restrict__ k,
    const float* __restrict__ cosb, const float* __restrict__ sinb)
{
  const int row = blockIdx.x;           // b*NL + l
  const int pos = row & (NL - 1);
  const float* cr = cosb + pos * HD;
  const float* sr = sinb + pos * HD;
  const int t = threadIdx.x;
  {
    const int head = t >> 4;
    const int d0 = (t & 15) << 2;
    u16* base = q + row * (NH * HD) + head * HD + d0;
    ushort4 a = *(const ushort4*)base;
    ushort4 b = *(const ushort4*)(base + 64);
    float4 c1 = *(const float4*)(cr + d0);
    float4 s1 = *(const float4*)(sr + d0);
    float4 c2 = *(const float4*)(cr + 64 + d0);
    float4 s2 = *(const float4*)(sr + 64 + d0);
    ushort4 o1, o2;
    o1.x = f2bf(bf2f(a.x)*c1.x - bf2f(b.x)*s1.x);
    o1.y = f2bf(bf2f(a.y)*c1.y - bf2f(b.y)*s1.y);
    o1.z = f2bf(bf2f(a.z)*c1.z - bf2f(b.z)*s1.z);
    o1.w = f2bf(bf2f(a.w)*c1.w - bf2f(b.w)*s1.w);
    o2.x = f2bf(bf2f(b.x)*c2.x + bf2f(a.x)*s2.x);
    o2.y = f2bf(bf2f(b.y)*c2.y + bf2f(a.y)*s2.y);
    o2.z = f2bf(bf2f(b.z)*c2.z + bf2f(a.z)*s2.z);
    o2.w = f2bf(bf2f(b.w)*c2.w + bf2f(a.w)*s2.w);
    *(ushort4*)base = o1;
    *(ushort4*)(base + 64) = o2;
  }
  {
    const int head = t >> 5;
    const int d0 = (t & 31) << 1;
    u16* base = k + row * (NKV * HD) + head * HD + d0;
    ushort2 a = *(const ushort2*)base;
    ushort2 b = *(const ushort2*)(base + 64);
    float2 c1 = *(const float2*)(cr + d0);
    float2 s1 = *(const float2*)(sr + d0);
    float2 c2 = *(const float2*)(cr + 64 + d0);
    float2 s2 = *(const float2*)(sr + 64 + d0);
    ushort2 o1, o2;
    o1.x = f2bf(bf2f(a.x)*c1.x - bf2f(b.x)*s1.x);
    o1.y = f2bf(bf2f(a.y)*c1.y - bf2f(b.y)*s1.y);
    o2.x = f2bf(bf2f(b.x)*c2.x + bf2f(a.x)*s2.x);
    o2.y = f2bf(bf2f(b.y)*c2.y + bf2f(a.y)*s2.y);
    *(ushort2*)base = o1;
    *(ushort2*)(base + 64) = o2;
  }
}

// ---------------- sliding-window attention (masked-fragment skip + setprio) ----------
__global__ __launch_bounds__(512) void attn_sw(const u16* __restrict__ q,
    const u16* __restrict__ k, const u16* __restrict__ v, u16* __restrict__ o)
{
  extern __shared__ u16 smem[];
  u16* kv0  = smem;               // 2 * 16384 u16 = 64KB
  u16* pbuf = smem + 2 * 16384;   // 8 * 4096 u16 = 64KB

  const int qb = blockIdx.x, h = blockIdx.y, b = blockIdx.z;
  const int kvh = h >> 1;
  const int tid = threadIdx.x, l = tid & 63, w = tid >> 6;
  const int lr = l & 15, lc = l >> 4;
  const int t0 = (qb == 0) ? 1 : 0;
  const int q0 = qb * 128;
  const int kst = NKV * HD;       // 1024

#pragma unroll
  for (int t = 0; t < 2; ++t){
    if (t >= t0){
      const int kb = qb - 1 + t;
      const u16* kbase = k + (b * NL + kb * 128) * kst + kvh * HD;
#pragma unroll
      for (int c = 0; c < 4; ++c){
        int off = c * 8192 + tid * 16;
        int row = off >> 8;
        int ch  = (off >> 4) & 15;
        int gch = ch ^ (row & 7);
        gld_lds16(kbase + row * kst + gch * 8, kv0 + t * 16384 + (off >> 1));
      }
    }
  }

  bf16x8 aq[4];
  {
    const int qrow = b * NL + q0 + w * 16 + lr;
#pragma unroll
    for (int kc = 0; kc < 4; ++kc)
      aq[kc] = *(const bf16x8*)(q + qrow * (NH * HD) + h * HD + kc * 32 + lc * 8);
  }
  __syncthreads();

  f32x4 sc[2][8] = {};
  __builtin_amdgcn_s_setprio(1);
#pragma unroll
  for (int t = 0; t < 2; ++t){
#pragma unroll
    for (int cb = 0; cb < 8; ++cb){
      const bool live = (t == 0) ? (t0 == 0 && cb >= w) : (cb <= w);
      if (live){
        f32x4 a = {};
#pragma unroll
        for (int kc = 0; kc < 4; ++kc){
          int row = cb * 16 + lr;
          bf16x8 bk = *(const bf16x8*)(kv0 + t * 16384 +
              ((row * 256 + ((kc * 64 + lc * 16) ^ ((row & 7) << 4))) >> 1));
          a = __builtin_amdgcn_mfma_f32_16x16x32_bf16(aq[kc], bk, a, 0, 0, 0);
        }
        sc[t][cb] = a;
      }
    }
  }
  __builtin_amdgcn_s_setprio(0);

  const float scale = 0.08838834764831845f;
  float mx[4] = {-3e38f, -3e38f, -3e38f, -3e38f};
#pragma unroll
  for (int t = 0; t < 2; ++t)
#pragma unroll
    for (int cb = 0; cb < 8; ++cb){
      const bool liveF = (t == 0) ? (t0 == 0 && cb >= w) : (cb <= w);
      if (liveF){
#pragma unroll
        for (int r = 0; r < 4; ++r){
          int rbl = w * 16 + lc * 4 + r;
          int c = cb * 16 + lr;
          bool keep = (t == 0) ? (c >= rbl) : (c <= rbl);
          float val = keep ? sc[t][cb][r] * scale : -1e30f;
          sc[t][cb][r] = val;
          mx[r] = fmaxf(mx[r], val);
        }
      }
    }
#pragma unroll
  for (int r = 0; r < 4; ++r){
    mx[r] = fmaxf(mx[r], __shfl_xor(mx[r], 1));
    mx[r] = fmaxf(mx[r], __shfl_xor(mx[r], 2));
    mx[r] = fmaxf(mx[r], __shfl_xor(mx[r], 4));
    mx[r] = fmaxf(mx[r], __shfl_xor(mx[r], 8));
  }

  float sm[4] = {0.f, 0.f, 0.f, 0.f};
  u16* pw = pbuf + w * 4096;
#pragma unroll
  for (int t = 0; t < 2; ++t)
#pragma unroll
    for (int cb = 0; cb < 8; ++cb){
      const bool liveC = (t == 0) ? (t0 == 0 && cb >= w) : (cb <= w);
      const bool readN = (t == 0) ? (t0 == 0 && (cb | 1) >= w) : ((cb & ~1) <= w);
      if (liveC){
#pragma unroll
        for (int r = 0; r < 4; ++r){
          float p = __expf(sc[t][cb][r] - mx[r]);
          sm[r] += p;
          int rr = lc * 4 + r;
          int colb = (t * 128 + cb * 16 + lr) * 2;
          pw[((rr * 512 + colb) ^ ((rr & 7) << 4)) >> 1] = f2bf(p);
        }
      } else if (readN){
#pragma unroll
        for (int r = 0; r < 4; ++r){
          int rr = lc * 4 + r;
          int colb = (t * 128 + cb * 16 + lr) * 2;
          pw[((rr * 512 + colb) ^ ((rr & 7) << 4)) >> 1] = 0;
        }
      }
    }
#pragma unroll
  for (int r = 0; r < 4; ++r){
    sm[r] += __shfl_xor(sm[r], 1);
    sm[r] += __shfl_xor(sm[r], 2);
    sm[r] += __shfl_xor(sm[r], 4);
    sm[r] += __shfl_xor(sm[r], 8);
  }

  __syncthreads();

  {
    const int key = tid & 127;
    const int h2 = tid >> 7;
#pragma unroll
    for (int t = 0; t < 2; ++t){
      if (t >= t0){
        const int kb = qb - 1 + t;
        const u16* vbase = v + (b * NL + kb * 128 + key) * kst + kvh * HD + h2 * 32;
        u16* dst = kv0 + t * 16384;
#pragma unroll
        for (int c2 = 0; c2 < 4; ++c2){
          union { uint4 v4; u16 s[8]; } u;
          u.v4 = *(const uint4*)(vbase + c2 * 8);
          int d0 = h2 * 32 + c2 * 8;
#pragma unroll
          for (int e = 0; e < 8; ++e){
            int d = d0 + e;
            dst[((d * 256 + key * 2) ^ ((d & 7) << 4)) >> 1] = u.s[e];
          }
        }
      }
    }
  }
  __syncthreads();

  f32x4 od[8] = {};
  __builtin_amdgcn_s_setprio(1);
#pragma unroll
  for (int kc = 0; kc < 8; ++kc){
    const int t = kc >> 2, kl = kc & 3;
    const bool live = (t == 0) ? (t0 == 0 && (kl * 2 + 1) >= w) : (kl * 2 <= w);
    if (live){
      int abyte = ((lr * 512 + (kc * 32 + lc * 8) * 2) ^ ((lr & 7) << 4));
      bf16x8 pa = *(const bf16x8*)(pbuf + w * 4096 + (abyte >> 1));
#pragma unroll
      for (int cb = 0; cb < 8; ++cb){
        int d = cb * 16 + lr;
        bf16x8 vb = *(const bf16x8*)(kv0 + t * 16384 +
            ((d * 256 + ((kl * 64 + lc * 16) ^ ((d & 7) << 4))) >> 1));
        od[cb] = __builtin_amdgcn_mfma_f32_16x16x32_bf16(pa, vb, od[cb], 0, 0, 0);
      }
    }
  }
  __builtin_amdgcn_s_setprio(0);

  float inv[4];
#pragma unroll
  for (int r = 0; r < 4; ++r) inv[r] = 1.0f / sm[r];
#pragma unroll
  for (int cb = 0; cb < 8; ++cb)
#pragma unroll
    for (int r = 0; r < 4; ++r){
      int orow = b * NL + q0 + w * 16 + lc * 4 + r;
      int ocol = h * HD + cb * 16 + lr;
      o[orow * (NH * HD) + ocol] = f2bf(od[cb][r] * inv[r]);
    }
}

// ---------------- launcher ----------------
extern "C" void kernel_launch(void* const* d_in, const int* in_sizes, int n_in,
                              void* d_out, int out_size, void* d_ws, size_t ws_size,
                              hipStream_t stream)
{
  const float* x    = (const float*)d_in[0];
  const float* cosb = (const float*)d_in[1];
  const float* sinb = (const float*)d_in[2];
  const float* wq   = (const float*)d_in[3];
  const float* wk   = (const float*)d_in[4];
  const float* wv   = (const float*)d_in[5];
  const float* wo   = (const float*)d_in[6];

  u16* p = (u16*)d_ws;
  u16* xb   = p; p += NB * NL * NDIM;
  u16* wqkv = p; p += (NH + 2 * NKV) * HD * NDIM;   // wq|wk|wv contiguous
  u16* wob  = p; p += NDIM * NH * HD;
  u16* qb   = p; p += NB * NL * NH * HD;
  u16* kb   = p; p += NB * NL * NKV * HD;
  u16* vb   = p; p += NB * NL * NKV * HD;
  u16* ab   = p; p += NB * NL * NH * HD;

  cast_all<<<2048, 256, 0, stream>>>(x, wq, wk, wv, wo, xb);

  hipFuncSetAttribute(reinterpret_cast<const void*>(gemm8p<2>),
                      hipFuncAttributeMaxDynamicSharedMemorySize, 131072);
  hipFuncSetAttribute(reinterpret_cast<const void*>(gemmWo),
                      hipFuncAttributeMaxDynamicSharedMemorySize, 131072);
  hipFuncSetAttribute(reinterpret_cast<const void*>(attn_sw),
                      hipFuncAttributeMaxDynamicSharedMemorySize, 131072);

  // fused QKV projection: M=4096, N=4096, K=2048
  gemm8p<2><<<dim3(16, 16), 512, 131072, stream>>>(xb, wqkv, qb, kb, vb,
                                                   NB * NL, (NH + 2 * NKV) * HD, NDIM);

  rope_kernel<<<NB * NL, 256, 0, stream>>>(qb, kb, cosb, sinb);

  attn_sw<<<dim3(NL / 128, NH, NB), 512, 131072, stream>>>(qb, kb, vb, ab);

  // output projection: M=4096, N=2048, K=2048 -> grid (8, 32) = 256 blocks
  gemmWo<<<dim3(8, 32), 512, 131072, stream>>>(ab, wob, (float*)d_out,
                                               NB * NL, NDIM, NH * HD);
}